// Round 21
// baseline (1564.888 us; speedup 1.0000x reference)
//
#include <hip/hip_runtime.h>
#include <hip/hip_bf16.h>
#include <math.h>

constexpr int Bn = 32, Nn = 4096, Dn = 512, NSn = 16, HIn = 128;
constexpr float kScale = 0.04419417382415922f; // 512^-0.5
constexpr float kEps = 1e-8f;

typedef __attribute__((ext_vector_type(8))) short short8;
typedef __attribute__((ext_vector_type(4))) float f32x4;

__device__ __forceinline__ float wred(float v) {
#pragma unroll
  for (int m = 32; m > 0; m >>= 1) v += __shfl_xor(v, m);
  return v;
}
__device__ __forceinline__ double wredd(double v) {
#pragma unroll
  for (int m = 32; m > 0; m >>= 1) v += __shfl_xor(v, m);
  return v;
}

// ---- bf16 split helpers (RNE) ----
__device__ __forceinline__ unsigned short f2bf(float x) {
  unsigned u = __float_as_uint(x);
  unsigned r = (u + 0x7fffu + ((u >> 16) & 1u)) >> 16;
  return (unsigned short)r;
}
__device__ __forceinline__ float bf2f(unsigned short h) {
  return __uint_as_float(((unsigned)h) << 16);
}
__device__ __forceinline__ unsigned packhm(float x) {
  unsigned short h = f2bf(x);
  unsigned short m = f2bf(x - bf2f(h));
  return (unsigned)h | ((unsigned)m << 16);
}
__device__ __forceinline__ unsigned pack2x(float x0, float x1, unsigned& mo) {
  unsigned p0 = packhm(x0), p1 = packhm(x1);
  mo = (p0 >> 16) | (p1 & 0xffff0000u);
  return (p0 & 0xffffu) | (p1 << 16);
}

// ---------------- transpose + bf16-hi + rowstat partials (inT u16 + Xp u16) ----------------
__global__ __launch_bounds__(256) void k_tsplit(const float* __restrict__ in, unsigned short* __restrict__ inT,
                                                unsigned short* __restrict__ Xp,
                                                float* __restrict__ psum, float* __restrict__ psqs) {
  __shared__ float tile[64][65];
  int b = blockIdx.z, j0 = blockIdx.x * 64, d0 = blockIdx.y * 64;
  int t = threadIdx.x;
  int rr = t >> 4, c4 = (t & 15) * 4;
  float4 v4[4];
#pragma unroll
  for (int e = 0; e < 4; ++e) {
    int r = e * 16 + rr;
    v4[e] = *reinterpret_cast<const float4*>(&in[((size_t)b * Nn + j0 + r) * Dn + d0 + c4]);
    tile[r][c4] = v4[e].x; tile[r][c4 + 1] = v4[e].y;
    tile[r][c4 + 2] = v4[e].z; tile[r][c4 + 3] = v4[e].w;
  }
  __syncthreads();
  float rs_s, rs_q;
  {
    int r = t >> 2, q = t & 3;
    float s = 0.0f, qq = 0.0f;
#pragma unroll
    for (int c = 0; c < 16; ++c) {
      float x = tile[r][q * 16 + c];
      s += x; qq += x * x;
    }
    s += __shfl_xor(s, 1); s += __shfl_xor(s, 2);
    qq += __shfl_xor(qq, 1); qq += __shfl_xor(qq, 2);
    rs_s = s; rs_q = qq;
  }
  unsigned short pv[16];
#pragma unroll
  for (int e = 0; e < 4; ++e) {
    pv[e * 4 + 0] = f2bf(v4[e].x);
    pv[e * 4 + 1] = f2bf(v4[e].y);
    pv[e * 4 + 2] = f2bf(v4[e].z);
    pv[e * 4 + 3] = f2bf(v4[e].w);
  }
  // direct Xp write (row-major, coalesced 8B/thread)
#pragma unroll
  for (int e = 0; e < 4; ++e) {
    int r = e * 16 + rr;
    uint2 o;
    o.x = (unsigned)pv[e * 4 + 0] | ((unsigned)pv[e * 4 + 1] << 16);
    o.y = (unsigned)pv[e * 4 + 2] | ((unsigned)pv[e * 4 + 3] << 16);
    *reinterpret_cast<uint2*>(&Xp[((size_t)b * Nn + j0 + r) * Dn + d0 + c4]) = o;
  }
  __syncthreads();
  unsigned short (*u16t)[130] = reinterpret_cast<unsigned short(*)[130]>(tile);
#pragma unroll
  for (int e = 0; e < 4; ++e) {
    int r = e * 16 + rr;
    u16t[r][c4] = pv[e * 4 + 0]; u16t[r][c4 + 1] = pv[e * 4 + 1];
    u16t[r][c4 + 2] = pv[e * 4 + 2]; u16t[r][c4 + 3] = pv[e * 4 + 3];
  }
  {
    int r = t >> 2, q = t & 3;
    if (q == 0) {
      size_t pi = ((size_t)b * Nn + j0 + r) * 8 + blockIdx.y;
      psum[pi] = rs_s;
      psqs[pi] = rs_q;
    }
  }
  __syncthreads();
#pragma unroll
  for (int e = 0; e < 4; ++e) {
    int dloc = e * 16 + rr;
    unsigned short o0 = u16t[c4][dloc], o1 = u16t[c4 + 1][dloc];
    unsigned short o2 = u16t[c4 + 2][dloc], o3 = u16t[c4 + 3][dloc];
    uint2 o;
    o.x = (unsigned)o0 | ((unsigned)o1 << 16);
    o.y = (unsigned)o2 | ((unsigned)o3 << 16);
    *reinterpret_cast<uint2*>(&inT[((size_t)b * Dn + d0 + dloc) * Nn + j0 + c4]) = o;
  }
}

// ---------------- slots init + LN_s fused (+ merged rowstat reduce) ----------------
__global__ __launch_bounds__(256) void k_initln(const float* __restrict__ smu, const float* __restrict__ sls,
                                                const float* __restrict__ noise,
                                                const float* __restrict__ lnsw, const float* __restrict__ lnsb,
                                                float* __restrict__ slots, float* __restrict__ sln,
                                                const float* __restrict__ psum, const float* __restrict__ psqs,
                                                float* __restrict__ mu, float* __restrict__ rsig) {
  int t = threadIdx.x;
  if (blockIdx.x >= Bn * NSn) {
    int row = (blockIdx.x - Bn * NSn) * 256 + t;
    float s = 0.0f, q = 0.0f;
#pragma unroll
    for (int e = 0; e < 8; ++e) {
      s += psum[(size_t)row * 8 + e];
      q += psqs[(size_t)row * 8 + e];
    }
    float m = s * (1.0f / 512.0f);
    float var = q * (1.0f / 512.0f) - m * m;
    mu[row] = m;
    rsig[row] = 1.0f / sqrtf(var + 1e-5f);
    return;
  }
  int r = blockIdx.x;
  __shared__ float red[8];
  float sn[2];
#pragma unroll
  for (int j = 0; j < 2; ++j) {
    int c = j * 256 + t;
    sn[j] = smu[c] + expf(sls[c]) * noise[(size_t)r * Dn + c];
  }
  float s = sn[0] + sn[1], q = sn[0] * sn[0] + sn[1] * sn[1];
  s = wred(s); q = wred(q);
  if ((t & 63) == 0) { red[t >> 6] = s; red[4 + (t >> 6)] = q; }
  __syncthreads();
  float S = red[0] + red[1] + red[2] + red[3];
  float Q = red[4] + red[5] + red[6] + red[7];
  float m = S * (1.0f / 512.0f);
  float rs = 1.0f / sqrtf(Q * (1.0f / 512.0f) - m * m + 1e-5f);
#pragma unroll
  for (int j = 0; j < 2; ++j) {
    int c = j * 256 + t;
    slots[(size_t)r * Dn + c] = sn[j];
    sln[(size_t)r * Dn + c] = (sn[j] - m) * rs * lnsw[c] + lnsb[c];
  }
}

// ---------------- small GEMM with register prefetch (f32 path, prologue T1) ----------------
template <bool TRANS, bool RELU, bool ADD>
__global__ __launch_bounds__(256) void k_gemm_sm(const float* __restrict__ A, const float* __restrict__ W,
                                                 const float* __restrict__ bias, float* __restrict__ out,
                                                 int Nc, int K) {
  __shared__ float as_[64][17];
  __shared__ float ws_[16][65];
  int m0 = blockIdx.y * 64, n0 = blockIdx.x * 64;
  int t = threadIdx.x, tx = t & 15, ty = t >> 4;
  float acc[4][4] = {};
  float pa[4], pw[4];
  auto loadA = [&](int k0) {
#pragma unroll
    for (int e = 0; e < 4; ++e) {
      int idx = t + e * 256;
      int r = idx >> 4, c = idx & 15;
      pa[e] = A[(size_t)(m0 + r) * K + k0 + c];
    }
  };
  auto loadW = [&](int k0) {
#pragma unroll
    for (int e = 0; e < 4; ++e) {
      int idx = t + e * 256;
      if (!TRANS) {
        int r = idx >> 6, c = idx & 63;
        pw[e] = W[(size_t)(k0 + r) * Nc + n0 + c];
      } else {
        int r = idx >> 4, c = idx & 15;
        pw[e] = W[(size_t)(n0 + r) * K + k0 + c];
      }
    }
  };
  loadA(0); loadW(0);
  for (int k0 = 0; k0 < K; k0 += 16) {
#pragma unroll
    for (int e = 0; e < 4; ++e) {
      int idx = t + e * 256;
      int r = idx >> 4, c = idx & 15;
      as_[r][c] = pa[e];
    }
#pragma unroll
    for (int e = 0; e < 4; ++e) {
      int idx = t + e * 256;
      if (!TRANS) {
        int r = idx >> 6, c = idx & 63;
        ws_[r][c] = pw[e];
      } else {
        int r = idx >> 4, c = idx & 15;
        ws_[c][r] = pw[e];
      }
    }
    __syncthreads();
    if (k0 + 16 < K) { loadA(k0 + 16); loadW(k0 + 16); }
#pragma unroll
    for (int kc = 0; kc < 16; ++kc) {
      float av[4], wv[4];
#pragma unroll
      for (int i = 0; i < 4; ++i) av[i] = as_[ty * 4 + i][kc];
#pragma unroll
      for (int j = 0; j < 4; ++j) wv[j] = ws_[kc][tx * 4 + j];
#pragma unroll
      for (int i = 0; i < 4; ++i)
#pragma unroll
        for (int j = 0; j < 4; ++j) acc[i][j] += av[i] * wv[j];
    }
    __syncthreads();
  }
#pragma unroll
  for (int i = 0; i < 4; ++i)
#pragma unroll
    for (int j = 0; j < 4; ++j) {
      int m = m0 + ty * 4 + i, n = n0 + tx * 4 + j;
      float v = acc[i][j] + (bias ? bias[n] : 0.0f);
      if (RELU) v = fmaxf(v, 0.0f);
      if (ADD) v += out[(size_t)m * Nc + n];
      out[(size_t)m * Nc + n] = v;
    }
}

// ---------------- transpose src[R][C] -> dst[C][R] (prologue, WhhT) ----------------
__global__ __launch_bounds__(256) void k_transp(const float* __restrict__ src, float* __restrict__ dst,
                                                int R, int C) {
  __shared__ float tile[64][65];
  int j0 = blockIdx.x * 64, i0 = blockIdx.y * 64;
  int t = threadIdx.x;
#pragma unroll
  for (int e = 0; e < 16; ++e) {
    int idx = t + e * 256;
    int r = idx >> 6, c = idx & 63;
    tile[r][c] = src[(size_t)(i0 + r) * C + j0 + c];
  }
  __syncthreads();
#pragma unroll
  for (int e = 0; e < 16; ++e) {
    int idx = t + e * 256;
    int r = idx >> 6, c = idx & 63;
    dst[(size_t)(j0 + r) * R + i0 + c] = tile[c][r];
  }
}

// ---------------- split-bf16 MFMA small GEMM: 64m x 64n tiles, K runtime ----------------
template <bool RELU, bool PARTIAL>
__global__ __launch_bounds__(256) void k_mm(const float* __restrict__ A, int lda,
                                            const float* __restrict__ W, int ldw,
                                            const float* __restrict__ bias,
                                            float* __restrict__ out, int ldo, int K) {
  __shared__ __align__(16) unsigned short as_h[64][40];
  __shared__ __align__(16) unsigned short as_m[64][40];
  __shared__ __align__(16) unsigned short ws_h[64][40];
  __shared__ __align__(16) unsigned short ws_m[64][40];
  int n0 = blockIdx.x * 64, m0 = blockIdx.y * 64, kbase = blockIdx.z * K;
  int t = threadIdx.x, w = t >> 6, l = t & 63;
  int lc = l & 15, lg = l >> 4, koff = lg * 8;

  f32x4 acc[4];
#pragma unroll
  for (int s = 0; s < 4; ++s) acc[s] = {0.0f, 0.0f, 0.0f, 0.0f};

  float2 na[4];
  float nw0[4], nw1[4];
  auto loadA = [&](int k0) {
#pragma unroll
    for (int e = 0; e < 4; ++e) {
      int idx = t + e * 256;
      int m = idx >> 4, kp = (idx & 15) * 2;
      na[e] = *reinterpret_cast<const float2*>(&A[(size_t)(m0 + m) * lda + kbase + k0 + kp]);
    }
  };
  auto loadW = [&](int k0) {
#pragma unroll
    for (int e = 0; e < 4; ++e) {
      int idx = t + e * 256;
      int kp = idx >> 6, n = idx & 63;
      nw0[e] = W[(size_t)(kbase + k0 + 2 * kp) * ldw + n0 + n];
      nw1[e] = W[(size_t)(kbase + k0 + 2 * kp + 1) * ldw + n0 + n];
    }
  };
  loadA(0); loadW(0);

  for (int k0 = 0; k0 < K; k0 += 32) {
#pragma unroll
    for (int e = 0; e < 4; ++e) {
      int idx = t + e * 256;
      int m = idx >> 4, kp = (idx & 15) * 2;
      unsigned mm;
      unsigned hm = pack2x(na[e].x, na[e].y, mm);
      *reinterpret_cast<unsigned*>(&as_h[m][kp]) = hm;
      *reinterpret_cast<unsigned*>(&as_m[m][kp]) = mm;
    }
#pragma unroll
    for (int e = 0; e < 4; ++e) {
      int idx = t + e * 256;
      int kp = idx >> 6, n = idx & 63;
      unsigned mm;
      unsigned hm = pack2x(nw0[e], nw1[e], mm);
      *reinterpret_cast<unsigned*>(&ws_h[n][kp * 2]) = hm;
      *reinterpret_cast<unsigned*>(&ws_m[n][kp * 2]) = mm;
    }
    __syncthreads();
    if (k0 + 32 < K) { loadA(k0 + 32); loadW(k0 + 32); }
    short8 ah = *reinterpret_cast<const short8*>(&as_h[w * 16 + lc][koff]);
    short8 am = *reinterpret_cast<const short8*>(&as_m[w * 16 + lc][koff]);
#pragma unroll
    for (int s = 0; s < 4; ++s) {
      short8 bh = *reinterpret_cast<const short8*>(&ws_h[s * 16 + lc][koff]);
      short8 bm = *reinterpret_cast<const short8*>(&ws_m[s * 16 + lc][koff]);
      acc[s] = __builtin_amdgcn_mfma_f32_16x16x32_bf16(ah, bh, acc[s], 0, 0, 0);
      acc[s] = __builtin_amdgcn_mfma_f32_16x16x32_bf16(ah, bm, acc[s], 0, 0, 0);
      acc[s] = __builtin_amdgcn_mfma_f32_16x16x32_bf16(am, bh, acc[s], 0, 0, 0);
    }
    __syncthreads();
  }

#pragma unroll
  for (int s = 0; s < 4; ++s) {
#pragma unroll
    for (int r = 0; r < 4; ++r) {
      int m = m0 + w * 16 + lg * 4 + r;
      int n = n0 + s * 16 + lc;
      float v = acc[s][r] + (bias ? bias[n] : 0.0f);
      if (RELU) v = fmaxf(v, 0.0f);
      if (PARTIAL)
        out[((size_t)blockIdx.z * 512 + m) * 512 + n] = v;
      else
        out[(size_t)m * ldo + n] = v;
    }
  }
}

// ---------------- fused GRU-gate GEMMs: z=0 gi = upd@T1+bcih, z=1 gh = slots@WhhT+bhh ----------------
__global__ __launch_bounds__(256) void k_ggm(const float* __restrict__ updb, const float* __restrict__ T1,
                                             const float* __restrict__ bcih, const float* __restrict__ slots,
                                             const float* __restrict__ WhhT, const float* __restrict__ bhh,
                                             float* __restrict__ gi, float* __restrict__ gh) {
  bool z = (blockIdx.z == 1);
  const float* A = z ? slots : updb;
  const float* W = z ? WhhT : T1;
  const float* bias = z ? bhh : bcih;
  float* out = z ? gh : gi;
  __shared__ __align__(16) unsigned short as_h[64][40];
  __shared__ __align__(16) unsigned short as_m[64][40];
  __shared__ __align__(16) unsigned short ws_h[64][40];
  __shared__ __align__(16) unsigned short ws_m[64][40];
  int n0 = blockIdx.x * 64, m0 = blockIdx.y * 64;
  int t = threadIdx.x, w = t >> 6, l = t & 63;
  int lc = l & 15, lg = l >> 4, koff = lg * 8;

  f32x4 acc[4];
#pragma unroll
  for (int s = 0; s < 4; ++s) acc[s] = {0.0f, 0.0f, 0.0f, 0.0f};

  float2 na[4];
  float nw0[4], nw1[4];
  auto loadA = [&](int k0) {
#pragma unroll
    for (int e = 0; e < 4; ++e) {
      int idx = t + e * 256;
      int m = idx >> 4, kp = (idx & 15) * 2;
      na[e] = *reinterpret_cast<const float2*>(&A[(size_t)(m0 + m) * 512 + k0 + kp]);
    }
  };
  auto loadW = [&](int k0) {
#pragma unroll
    for (int e = 0; e < 4; ++e) {
      int idx = t + e * 256;
      int kp = idx >> 6, n = idx & 63;
      nw0[e] = W[(size_t)(k0 + 2 * kp) * 1536 + n0 + n];
      nw1[e] = W[(size_t)(k0 + 2 * kp + 1) * 1536 + n0 + n];
    }
  };
  loadA(0); loadW(0);

  for (int k0 = 0; k0 < 512; k0 += 32) {
#pragma unroll
    for (int e = 0; e < 4; ++e) {
      int idx = t + e * 256;
      int m = idx >> 4, kp = (idx & 15) * 2;
      unsigned mm;
      unsigned hm = pack2x(na[e].x, na[e].y, mm);
      *reinterpret_cast<unsigned*>(&as_h[m][kp]) = hm;
      *reinterpret_cast<unsigned*>(&as_m[m][kp]) = mm;
    }
#pragma unroll
    for (int e = 0; e < 4; ++e) {
      int idx = t + e * 256;
      int kp = idx >> 6, n = idx & 63;
      unsigned mm;
      unsigned hm = pack2x(nw0[e], nw1[e], mm);
      *reinterpret_cast<unsigned*>(&ws_h[n][kp * 2]) = hm;
      *reinterpret_cast<unsigned*>(&ws_m[n][kp * 2]) = mm;
    }
    __syncthreads();
    if (k0 + 32 < 512) { loadA(k0 + 32); loadW(k0 + 32); }
    short8 ah = *reinterpret_cast<const short8*>(&as_h[w * 16 + lc][koff]);
    short8 am = *reinterpret_cast<const short8*>(&as_m[w * 16 + lc][koff]);
#pragma unroll
    for (int s = 0; s < 4; ++s) {
      short8 bh = *reinterpret_cast<const short8*>(&ws_h[s * 16 + lc][koff]);
      short8 bm = *reinterpret_cast<const short8*>(&ws_m[s * 16 + lc][koff]);
      acc[s] = __builtin_amdgcn_mfma_f32_16x16x32_bf16(ah, bh, acc[s], 0, 0, 0);
      acc[s] = __builtin_amdgcn_mfma_f32_16x16x32_bf16(ah, bm, acc[s], 0, 0, 0);
      acc[s] = __builtin_amdgcn_mfma_f32_16x16x32_bf16(am, bh, acc[s], 0, 0, 0);
    }
    __syncthreads();
  }

#pragma unroll
  for (int s = 0; s < 4; ++s) {
#pragma unroll
    for (int r = 0; r < 4; ++r) {
      int m = m0 + w * 16 + lg * 4 + r;
      int n = n0 + s * 16 + lc;
      out[(size_t)m * 1536 + n] = acc[s][r] + bias[n];
    }
  }
}

// ---------------- qkt = sln @ Ms + vb_s via MFMA, u16 hi-only out (+ merged alpha/beta) ----------------
__global__ __launch_bounds__(256) void k_qum_ab(const float* __restrict__ A, const float* __restrict__ Ms,
                                                const float* __restrict__ vb_s, unsigned short* __restrict__ qkt,
                                                const float* __restrict__ avec, const float* __restrict__ bvec,
                                                const float* __restrict__ aconst, const float* __restrict__ bconst,
                                                float* __restrict__ alpha, float* __restrict__ beta) {
  __shared__ __align__(16) unsigned short as_h[64][40];
  __shared__ __align__(16) unsigned short as_m[64][40];
  __shared__ __align__(16) unsigned short ws_h[64][40];
  __shared__ __align__(16) unsigned short ws_m[64][40];
  int t = threadIdx.x, w = t >> 6, l = t & 63;

  if (blockIdx.x >= 64) {
    int abid = (blockIdx.x - 64) * 8 + blockIdx.y;
    int lane = l;
#pragma unroll
    for (int gi = 0; gi < 4; ++gi) {
      int g = abid * 16 + w * 4 + gi;
      int hi = g & 127, b = g >> 7;
      int h = hi >> 4, i = hi & 15;
      const float4* sp = reinterpret_cast<const float4*>(A + (size_t)(b * NSn + i) * Dn) + lane * 2;
      const float4* ap = reinterpret_cast<const float4*>(avec + h * 512) + lane * 2;
      const float4* bp = reinterpret_cast<const float4*>(bvec + h * 512) + lane * 2;
      float4 s0 = sp[0], s1 = sp[1], a0 = ap[0], a1 = ap[1], b0 = bp[0], b1 = bp[1];
      float pa = s0.x*a0.x + s0.y*a0.y + s0.z*a0.z + s0.w*a0.w + s1.x*a1.x + s1.y*a1.y + s1.z*a1.z + s1.w*a1.w;
      float pb = s0.x*b0.x + s0.y*b0.y + s0.z*b0.z + s0.w*b0.w + s1.x*b1.x + s1.y*b1.y + s1.z*b1.z + s1.w*b1.w;
      pa = wred(pa); pb = wred(pb);
      if (lane == 0) {
        alpha[g] = pa + aconst[h];
        beta[g] = pb + bconst[h];
      }
    }
    return;
  }

  int n0 = blockIdx.x * 64, m0 = blockIdx.y * 64;
  int lc = l & 15, lg = l >> 4, koff = lg * 8;

  f32x4 acc[4];
#pragma unroll
  for (int s = 0; s < 4; ++s) acc[s] = {0.0f, 0.0f, 0.0f, 0.0f};

  float2 na[4];
  float nw0[4], nw1[4];
  auto loadA = [&](int k0) {
#pragma unroll
    for (int e = 0; e < 4; ++e) {
      int idx = t + e * 256;
      int m = idx >> 4, kp = (idx & 15) * 2;
      na[e] = *reinterpret_cast<const float2*>(&A[(size_t)(m0 + m) * 512 + k0 + kp]);
    }
  };
  auto loadW = [&](int k0) {
#pragma unroll
    for (int e = 0; e < 4; ++e) {
      int idx = t + e * 256;
      int kp = idx >> 6, n = idx & 63;
      nw0[e] = Ms[(size_t)(k0 + 2 * kp) * 4096 + n0 + n];
      nw1[e] = Ms[(size_t)(k0 + 2 * kp + 1) * 4096 + n0 + n];
    }
  };
  loadA(0); loadW(0);

  for (int k0 = 0; k0 < 512; k0 += 32) {
#pragma unroll
    for (int e = 0; e < 4; ++e) {
      int idx = t + e * 256;
      int m = idx >> 4, kp = (idx & 15) * 2;
      unsigned mm;
      unsigned hm = pack2x(na[e].x, na[e].y, mm);
      *reinterpret_cast<unsigned*>(&as_h[m][kp]) = hm;
      *reinterpret_cast<unsigned*>(&as_m[m][kp]) = mm;
    }
#pragma unroll
    for (int e = 0; e < 4; ++e) {
      int idx = t + e * 256;
      int kp = idx >> 6, n = idx & 63;
      unsigned mm;
      unsigned hm = pack2x(nw0[e], nw1[e], mm);
      *reinterpret_cast<unsigned*>(&ws_h[n][kp * 2]) = hm;
      *reinterpret_cast<unsigned*>(&ws_m[n][kp * 2]) = mm;
    }
    __syncthreads();
    if (k0 + 32 < 512) { loadA(k0 + 32); loadW(k0 + 32); }
    short8 ah = *reinterpret_cast<const short8*>(&as_h[w * 16 + lc][koff]);
    short8 am = *reinterpret_cast<const short8*>(&as_m[w * 16 + lc][koff]);
#pragma unroll
    for (int s = 0; s < 4; ++s) {
      short8 bh = *reinterpret_cast<const short8*>(&ws_h[s * 16 + lc][koff]);
      short8 bm = *reinterpret_cast<const short8*>(&ws_m[s * 16 + lc][koff]);
      acc[s] = __builtin_amdgcn_mfma_f32_16x16x32_bf16(ah, bh, acc[s], 0, 0, 0);
      acc[s] = __builtin_amdgcn_mfma_f32_16x16x32_bf16(ah, bm, acc[s], 0, 0, 0);
      acc[s] = __builtin_amdgcn_mfma_f32_16x16x32_bf16(am, bh, acc[s], 0, 0, 0);
    }
    __syncthreads();
  }

#pragma unroll
  for (int s = 0; s < 4; ++s) {
#pragma unroll
    for (int r = 0; r < 4; ++r) {
      int m = m0 + w * 16 + lg * 4 + r;
      int n = n0 + s * 16 + lc;
      int bb = m >> 4, isl = m & 15, h = n >> 9, d = n & 511;
      qkt[((size_t)bb * HIn + h * 16 + isl) * Dn + d] = f2bf(acc[s][r] + vb_s[n]);
    }
  }
}

// ---------------- W2 reduce + bias + residual + LN_s fused -> slots, sln ----------------
__global__ __launch_bounds__(256) void k_w2ln(const float* __restrict__ part, const float* __restrict__ b2,
                                              float* __restrict__ slots, float* __restrict__ sln,
                                              const float* __restrict__ lnsw, const float* __restrict__ lnsb) {
  int r = blockIdx.x, t = threadIdx.x;
  __shared__ float red[8];
  float sn[2];
#pragma unroll
  for (int j = 0; j < 2; ++j) {
    int c = j * 256 + t;
    size_t idx = (size_t)r * 512 + c;
    sn[j] = part[idx] + part[262144 + idx] + part[2 * 262144 + idx] + part[3 * 262144 + idx]
          + b2[c] + slots[idx];
  }
  float s = sn[0] + sn[1], q = sn[0] * sn[0] + sn[1] * sn[1];
  s = wred(s); q = wred(q);
  if ((t & 63) == 0) { red[t >> 6] = s; red[4 + (t >> 6)] = q; }
  __syncthreads();
  float S = red[0] + red[1] + red[2] + red[3];
  float Q = red[4] + red[5] + red[6] + red[7];
  float m = S * (1.0f / 512.0f);
  float rs = 1.0f / sqrtf(Q * (1.0f / 512.0f) - m * m + 1e-5f);
#pragma unroll
  for (int j = 0; j < 2; ++j) {
    int c = j * 256 + t;
    size_t idx = (size_t)r * 512 + c;
    slots[idx] = sn[j];
    sln[idx] = (sn[j] - m) * rs * lnsw[c] + lnsb[c];
  }
}

// ---------------- M_h = Wq_h @ Wk_h^T per head (raw) -> Ms[k*4096 + h*512 + d] ----------------
__global__ __launch_bounds__(256) void k_mh(const float* __restrict__ Wq, const float* __restrict__ Wk,
                                            float* __restrict__ Ms) {
  int h = blockIdx.z, k0 = blockIdx.y * 64, d0 = blockIdx.x * 64;
  __shared__ float qa[64][65];
  __shared__ float ka[64][65];
  int t = threadIdx.x, tx = t & 15, ty = t >> 4;
#pragma unroll
  for (int e = 0; e < 16; ++e) {
    int idx = t + e * 256;
    int r = idx >> 6, c = idx & 63;
    qa[c][r] = Wq[(size_t)(k0 + r) * Dn + h * 64 + c];
    ka[c][r] = Wk[(size_t)(d0 + r) * Dn + h * 64 + c];
  }
  __syncthreads();
  float acc[4][4] = {};
#pragma unroll 4
  for (int c = 0; c < 64; ++c) {
    float av[4], bv[4];
#pragma unroll
    for (int i = 0; i < 4; ++i) av[i] = qa[c][ty * 4 + i];
#pragma unroll
    for (int j = 0; j < 4; ++j) bv[j] = ka[c][tx * 4 + j];
#pragma unroll
    for (int i = 0; i < 4; ++i)
#pragma unroll
      for (int j = 0; j < 4; ++j) acc[i][j] += av[i] * bv[j];
  }
#pragma unroll
  for (int i = 0; i < 4; ++i)
#pragma unroll
    for (int j = 0; j < 4; ++j)
      Ms[(size_t)(k0 + ty * 4 + i) * 4096 + h * 512 + d0 + tx * 4 + j] = acc[i][j];
}

// ---------------- vbias + bcih merged ----------------
__global__ __launch_bounds__(256) void k_vbias_bcih(const float* __restrict__ Wk, const float* __restrict__ bq,
                                                    const float* __restrict__ lnw, float* __restrict__ vb_raw,
                                                    float* __restrict__ vb_s, const float* __restrict__ bc,
                                                    const float* __restrict__ Wih, const float* __restrict__ bih,
                                                    float* __restrict__ bcih) {
  __shared__ float cbuf[512];
  int t = threadIdx.x;
  if (blockIdx.x < 2) {
    cbuf[t] = bq[t]; cbuf[256 + t] = bq[256 + t];
    __syncthreads();
    int d = blockIdx.x * 256 + t;
    float vb[8] = {};
    const float4* wr = reinterpret_cast<const float4*>(Wk + (size_t)d * Dn);
#pragma unroll 8
    for (int c4 = 0; c4 < 128; ++c4) {
      float4 wv = wr[c4];
      int h = c4 >> 4;
      int c = c4 * 4;
      vb[h] += wv.x * cbuf[c] + wv.y * cbuf[c + 1] + wv.z * cbuf[c + 2] + wv.w * cbuf[c + 3];
    }
    float lw = lnw[d];
#pragma unroll
    for (int h = 0; h < 8; ++h) {
      vb_raw[h * 512 + d] = vb[h];
      vb_s[h * 512 + d] = kScale * lw * vb[h];
    }
  } else {
    cbuf[t] = bc[t]; cbuf[256 + t] = bc[256 + t];
    __syncthreads();
    int n = (blockIdx.x - 2) * 256 + t;
    const float4* wr = reinterpret_cast<const float4*>(Wih + (size_t)n * Dn);
    float a = 0.0f;
#pragma unroll 8
    for (int c4 = 0; c4 < 128; ++c4) {
      float4 wv = wr[c4];
      int c = c4 * 4;
      a += wv.x * cbuf[c] + wv.y * cbuf[c + 1] + wv.z * cbuf[c + 2] + wv.w * cbuf[c + 3];
    }
    bcih[n] = a + bih[n];
  }
}

// ---------------- mfold + consts merged ----------------
__global__ __launch_bounds__(256) void k_mfold_consts(float* __restrict__ Ms, const float* __restrict__ Wq,
                                                      const float* __restrict__ bk, const float* __restrict__ lnw,
                                                      const float* __restrict__ lnb, float* __restrict__ avec,
                                                      float* __restrict__ bvec, const float* __restrict__ vb_raw,
                                                      const float* __restrict__ bq, float* __restrict__ aconst,
                                                      float* __restrict__ bconst) {
  int t = threadIdx.x;
  if (blockIdx.x < 16) {
    __shared__ float lws[512], lbs[512], bks[512];
    lws[t] = lnw[t]; lws[256 + t] = lnw[256 + t];
    lbs[t] = lnb[t]; lbs[256 + t] = lnb[256 + t];
    bks[t] = bk[t]; bks[256 + t] = bk[256 + t];
    __syncthreads();
    int g = blockIdx.x * 256 + t;
    int k = g >> 3, h = g & 7;
    float* mr = Ms + (size_t)k * 4096 + h * 512;
    float mlnb = 0.0f, mlnw = 0.0f;
    for (int d = 0; d < 512; d += 4) {
      float4 m4 = *reinterpret_cast<const float4*>(mr + d);
      mlnb += m4.x * lbs[d] + m4.y * lbs[d + 1] + m4.z * lbs[d + 2] + m4.w * lbs[d + 3];
      mlnw += m4.x * lws[d] + m4.y * lws[d + 1] + m4.z * lws[d + 2] + m4.w * lws[d + 3];
      float4 o4 = {m4.x * kScale * lws[d], m4.y * kScale * lws[d + 1],
                   m4.z * kScale * lws[d + 2], m4.w * kScale * lws[d + 3]};
      *reinterpret_cast<float4*>(mr + d) = o4;
    }
    float wqdot = 0.0f;
    const float* qr = Wq + (size_t)k * Dn + h * 64;
    for (int c = 0; c < 64; c += 4) {
      float4 q4 = *reinterpret_cast<const float4*>(qr + c);
      wqdot += q4.x * bks[h * 64 + c] + q4.y * bks[h * 64 + c + 1] +
               q4.z * bks[h * 64 + c + 2] + q4.w * bks[h * 64 + c + 3];
    }
    avec[h * 512 + k] = kScale * (mlnb + wqdot);
    bvec[h * 512 + k] = kScale * mlnw;
  } else {
    __shared__ float r1[256], r2[256], r3[256];
    for (int h = 0; h < 8; ++h) {
      float p1 = 0.0f, p2 = 0.0f, p3 = 0.0f;
      for (int d = t; d < 512; d += 256) {
        float vr = vb_raw[h * 512 + d];
        p1 += lnb[d] * vr;
        p2 += lnw[d] * vr;
      }
      if (t < 64) p3 = bq[h * 64 + t] * bk[h * 64 + t];
      r1[t] = p1; r2[t] = p2; r3[t] = p3;
      __syncthreads();
      for (int s = 128; s > 0; s >>= 1) {
        if (t < s) { r1[t] += r1[t + s]; r2[t] += r2[t + s]; r3[t] += r3[t + s]; }
        __syncthreads();
      }
      if (t == 0) {
        aconst[h] = kScale * (r1[0] + r3[0]);
        bconst[h] = kScale * r2[0];
      }
      __syncthreads();
    }
  }
}

// ---------------- dots: LDS-free GEMM (X from Xp, U from qkt, all direct fragments) ----------------
// A output: bf16-hi only (u16)
__global__ __launch_bounds__(256) void k_dots(const unsigned short* __restrict__ Xp, const unsigned short* __restrict__ qkt,
                                              const float* __restrict__ alpha, const float* __restrict__ beta,
                                              const float* __restrict__ mu, const float* __restrict__ rsig,
                                              unsigned short* __restrict__ A, float* __restrict__ Spart,
                                              float* __restrict__ c1part) {
  __shared__ __align__(16) float redbuf[1536];

  int b = blockIdx.y, jt = blockIdx.x, j0 = jt * 128;
  int t = threadIdx.x, w = t >> 6, l = t & 63;
  int lc = l & 15, lg = l >> 4, koff = lg * 8;
  const size_t ubase = (size_t)b * HIn * Dn;

  f32x4 acc[2][8];
#pragma unroll
  for (int i = 0; i < 2; ++i)
#pragma unroll
    for (int j2 = 0; j2 < 8; ++j2) acc[i][j2] = {0.0f, 0.0f, 0.0f, 0.0f};

  int row0 = w * 32 + lc, row1 = row0 + 16;
  const unsigned short* xr0 = &Xp[((size_t)b * Nn + j0 + row0) * Dn + koff];
  const unsigned short* xr1 = &Xp[((size_t)b * Nn + j0 + row1) * Dn + koff];
  const unsigned short* ur = &qkt[ubase + (size_t)lc * Dn + koff];

#pragma unroll 4
  for (int k0 = 0; k0 < 512; k0 += 32) {
    short8 a0 = *reinterpret_cast<const short8*>(&xr0[k0]);
    short8 a1 = *reinterpret_cast<const short8*>(&xr1[k0]);
#pragma unroll
    for (int ht = 0; ht < 8; ++ht) {
      short8 bh = *reinterpret_cast<const short8*>(&ur[(size_t)(ht * 16) * Dn + k0]);
      acc[0][ht] = __builtin_amdgcn_mfma_f32_16x16x32_bf16(a0, bh, acc[0][ht], 0, 0, 0);
      acc[1][ht] = __builtin_amdgcn_mfma_f32_16x16x32_bf16(a1, bh, acc[1][ht], 0, 0, 0);
    }
  }

  float* rsL = redbuf;
  float* muL = rsL + 128;
  float* aL = rsL + 256;
  float* bL = rsL + 384;
  float (*sredS)[128] = reinterpret_cast<float(*)[128]>(rsL + 512);
  float (*sredC)[128] = reinterpret_cast<float(*)[128]>(rsL + 512 + 4 * 128);
  if (t < 128) {
    rsL[t] = rsig[(size_t)b * Nn + j0 + t];
    muL[t] = mu[(size_t)b * Nn + j0 + t];
    aL[t] = alpha[b * HIn + t];
    bL[t] = beta[b * HIn + t];
  }
  __syncthreads();

  float sS[8] = {}, sC[8] = {};
#pragma unroll
  for (int jt2 = 0; jt2 < 2; ++jt2) {
    int jbase = w * 32 + jt2 * 16 + lg * 4;
#pragma unroll
    for (int ht = 0; ht < 8; ++ht) {
      int hi = ht * 16 + lc;
      float av = aL[hi], bv = bL[hi];
      float v[4], rs4[4], mr4[4];
#pragma unroll
      for (int r = 0; r < 4; ++r) {
        int jr = jbase + r;
        rs4[r] = rsL[jr];
        mr4[r] = muL[jr] * rs4[r];
        v[r] = acc[jt2][ht][r] * rs4[r] + av - mr4[r] * bv;
      }
      float mx[4] = {v[0], v[1], v[2], v[3]};
#pragma unroll
      for (int m = 1; m <= 8; m <<= 1)
#pragma unroll
        for (int r = 0; r < 4; ++r) mx[r] = fmaxf(mx[r], __shfl_xor(mx[r], m));
      float e4[4], ss[4];
#pragma unroll
      for (int r = 0; r < 4; ++r) { e4[r] = expf(v[r] - mx[r]); ss[r] = e4[r]; }
#pragma unroll
      for (int m = 1; m <= 8; m <<= 1)
#pragma unroll
        for (int r = 0; r < 4; ++r) ss[r] += __shfl_xor(ss[r], m);
      float ps = 0.0f, pc = 0.0f;
      float p0 = e4[0] / ss[0] + kEps, p1 = e4[1] / ss[1] + kEps;
      float p2 = e4[2] / ss[2] + kEps, p3 = e4[3] / ss[3] + kEps;
      unsigned h01 = (unsigned)f2bf(p0 * rs4[0]) | ((unsigned)f2bf(p1 * rs4[1]) << 16);
      unsigned h23 = (unsigned)f2bf(p2 * rs4[2]) | ((unsigned)f2bf(p3 * rs4[3]) << 16);
      uint2 o2 = {h01, h23};
      ps = p0 + p1 + p2 + p3;
      pc = p0 * mr4[0] + p1 * mr4[1] + p2 * mr4[2] + p3 * mr4[3];
      *reinterpret_cast<uint2*>(&A[(size_t)(b * HIn + hi) * Nn + j0 + jbase]) = o2;
      ps += __shfl_xor(ps, 16); ps += __shfl_xor(ps, 32);
      pc += __shfl_xor(pc, 16); pc += __shfl_xor(pc, 32);
      sS[ht] += ps; sC[ht] += pc;
    }
  }
  if (l < 16) {
#pragma unroll
    for (int ht = 0; ht < 8; ++ht) {
      sredS[w][ht * 16 + l] = sS[ht];
      sredC[w][ht * 16 + l] = sC[ht];
    }
  }
  __syncthreads();
  if (t < 128) {
    float s_ = sredS[0][t] + sredS[1][t] + sredS[2][t] + sredS[3][t];
    float c_ = sredC[0][t] + sredC[1][t] + sredC[2][t] + sredC[3][t];
    int sub = (b * 32 + jt) * HIn + t;
    Spart[sub] = s_;
    c1part[sub] = c_;
  }
}

// ---------------- AX = A @ X; LDS-free; K-split x2; XCD-grouped block remap ----------------
__global__ __launch_bounds__(256) void k_ax(const unsigned short* __restrict__ Au, const unsigned short* __restrict__ inT,
                                            float* __restrict__ AXp) {
  // remap: blocks sharing the same A half-tile (kp,b) land on the same XCD
  int lid = blockIdx.x + 8 * (blockIdx.y + 2 * blockIdx.z);   // 0..511
  int d0 = (lid >> 6) * 64;
  int rest = lid & 63;
  int kp = rest & 1, b = rest >> 1;

  int t = threadIdx.x, w = t >> 6, l = t & 63;
  int lc = l & 15, lg = l >> 4, koff = lg * 8;

  f32x4 acc[2][4];
#pragma unroll
  for (int i = 0; i < 2; ++i)
#pragma unroll
    for (int j2 = 0; j2 < 4; ++j2) acc[i][j2] = {0.0f, 0.0f, 0.0f, 0.0f};

  int hi0 = w * 32 + lc, hi1 = hi0 + 16;
  const unsigned short* ar0 = &Au[(size_t)b * HIn * Nn + (size_t)hi0 * Nn + (size_t)kp * 2048 + koff];
  const unsigned short* ar1 = &Au[(size_t)b * HIn * Nn + (size_t)hi1 * Nn + (size_t)kp * 2048 + koff];
  const unsigned short* xr = &inT[((size_t)b * Dn + d0 + lc) * Nn + (size_t)kp * 2048 + koff];

#pragma unroll 4
  for (int c0 = 0; c0 < 2048; c0 += 32) {
    short8 a0 = *reinterpret_cast<const short8*>(&ar0[c0]);
    short8 a1 = *reinterpret_cast<const short8*>(&ar1[c0]);
#pragma unroll
    for (int dt = 0; dt < 4; ++dt) {
      short8 bh = *reinterpret_cast<const short8*>(&xr[(size_t)(dt * 16) * Nn + c0]);
      acc[0][dt] = __builtin_amdgcn_mfma_f32_16x16x32_bf16(a0, bh, acc[0][dt], 0, 0, 0);
      acc[1][dt] = __builtin_amdgcn_mfma_f32_16x16x32_bf16(a1, bh, acc[1][dt], 0, 0, 0);
    }
  }

  const size_t obase = (((size_t)kp * Bn + b) * HIn) * Dn + d0;
#pragma unroll
  for (int jt2 = 0; jt2 < 2; ++jt2) {
#pragma unroll
    for (int dt = 0; dt < 4; ++dt) {
#pragma unroll
      for (int r = 0; r < 4; ++r) {
        int hi = w * 32 + jt2 * 16 + lg * 4 + r;
        int d = dt * 16 + lc;
        AXp[obase + (size_t)hi * Dn + d] = acc[jt2][dt][r];
      }
    }
  }
}

// ---------------- upd = ((w*(G-c1)/S + b) @ Wv_h) + bv, S/c1 reduced inline ----------------
__global__ __launch_bounds__(256) void k_updS(const float* __restrict__ AXp, const float* __restrict__ Spart,
                                              const float* __restrict__ c1part, const float* __restrict__ lnw,
                                              const float* __restrict__ lnb, const float* __restrict__ Wv,
                                              const float* __restrict__ bv, float* __restrict__ upd) {
  int b = blockIdx.y, hi = blockIdx.x, h = hi >> 4, i = hi & 15;
  __shared__ float vx[512];
  __shared__ float red[256];
  __shared__ float sSC[2];
  int t = threadIdx.x;
  if (t < 64) {
    float vs = 0.0f, vc = 0.0f;
    if (t < 32) {
      vs = Spart[(size_t)(b * 32 + t) * HIn + hi];
      vc = c1part[(size_t)(b * 32 + t) * HIn + hi];
    }
    vs = wred(vs); vc = wred(vc);
    if (t == 0) { sSC[0] = vs; sSC[1] = vc; }
  }
  __syncthreads();
  float c1v = sSC[1];
  float invS = 1.0f / sSC[0];
  for (int d = t; d < Dn; d += 256) {
    float G = AXp[((size_t)(0 * Bn + b) * HIn + hi) * Dn + d]
            + AXp[((size_t)(1 * Bn + b) * HIn + hi) * Dn + d];
    vx[d] = lnw[d] * (G - c1v) * invS + lnb[d];
  }
  __syncthreads();
  int cc = t & 63, qd = t >> 6;
  float p = 0.0f;
  for (int d = qd * 128; d < qd * 128 + 128; ++d) p += vx[d] * Wv[(size_t)d * Dn + h * 64 + cc];
  red[t] = p;
  __syncthreads();
  if (qd == 0) {
    float v = red[cc] + red[64 + cc] + red[128 + cc] + red[192 + cc] + bv[h * 64 + cc];
    upd[(size_t)(b * NSn + i) * Dn + h * 64 + cc] = v;
  }
}

// ---------------- GRU pointwise + LN_ff fused ----------------
__global__ __launch_bounds__(256) void k_gruln(const float* __restrict__ gi, const float* __restrict__ gh,
                                               float* __restrict__ slots, float* __restrict__ slnff,
                                               const float* __restrict__ lnffw, const float* __restrict__ lnffb) {
  int r = blockIdx.x, t = threadIdx.x;
  __shared__ float red[8];
  float sn[2];
#pragma unroll
  for (int j = 0; j < 2; ++j) {
    int c = j * 256 + t;
    float gir = gi[(size_t)r * 1536 + c];
    float giz = gi[(size_t)r * 1536 + 512 + c];
    float gin = gi[(size_t)r * 1536 + 1024 + c];
    float ghr = gh[(size_t)r * 1536 + c];
    float ghz = gh[(size_t)r * 1536 + 512 + c];
    float ghn = gh[(size_t)r * 1536 + 1024 + c];
    float rg = 1.0f / (1.0f + expf(-(gir + ghr)));
    float zg = 1.0f / (1.0f + expf(-(giz + ghz)));
    float ng = tanhf(gin + rg * ghn);
    sn[j] = (1.0f - zg) * ng + zg * slots[(size_t)r * Dn + c];
  }
  float s = sn[0] + sn[1], q = sn[0] * sn[0] + sn[1] * sn[1];
  s = wred(s); q = wred(q);
  if ((t & 63) == 0) { red[t >> 6] = s; red[4 + (t >> 6)] = q; }
  __syncthreads();
  float S = red[0] + red[1] + red[2] + red[3];
  float Q = red[4] + red[5] + red[6] + red[7];
  float m = S * (1.0f / 512.0f);
  float rs = 1.0f / sqrtf(Q * (1.0f / 512.0f) - m * m + 1e-5f);
#pragma unroll
  for (int j = 0; j < 2; ++j) {
    int c = j * 256 + t;
    slots[(size_t)r * Dn + c] = sn[j];
    slnff[(size_t)r * Dn + c] = (sn[j] - m) * rs * lnffw[c] + lnffb[c];
  }
}

// ---------------- hard route + gather output (keep gate + scalars inlined) ----------------
__global__ __launch_bounds__(256) void k_route_out(const float* __restrict__ in, const float* __restrict__ slots,
                                                   const float* __restrict__ lnw, const float* __restrict__ lnb,
                                                   const float* __restrict__ Wkeep, const float* __restrict__ gk,
                                                   const float* __restrict__ mu, const float* __restrict__ rsig,
                                                   const float* __restrict__ g_route, float* __restrict__ out) {
  int b = blockIdx.y, j0 = blockIdx.x * 128;
  __shared__ __align__(16) float sl[16 * 516];
  __shared__ __align__(16) float lw[512];
  __shared__ __align__(16) float xs[16][132];
  __shared__ double lgd[128][17];
  __shared__ int besti[128];
  __shared__ double swdL[16], sbdL[16];
  int t = threadIdx.x, tx = t & 15, ty = t >> 4;
  int wv_ = t >> 6, lane = t & 63;

  for (int idx = t; idx < 2048; idx += 256) {
    int i = idx >> 7, c = idx & 127;
    *reinterpret_cast<float4*>(&sl[i * 516 + c * 4]) =
        *reinterpret_cast<const float4*>(&slots[(size_t)(b * NSn + i) * Dn + c * 4]);
  }
  if (t < 128)
    *reinterpret_cast<float4*>(&lw[t * 4]) = *reinterpret_cast<const float4*>(&lnw[t * 4]);
  __syncthreads();

#pragma unroll
  for (int qi = 0; qi < 4; ++qi) {
    int i = wv_ * 4 + qi;
    float* srow = &sl[i * 516];
    float sv[8];
#pragma unroll
    for (int e = 0; e < 8; ++e) sv[e] = srow[lane * 8 + e];
    double d0 = 0.0, d1 = 0.0;
#pragma unroll
    for (int e = 0; e < 8; ++e) {
      int d = lane * 8 + e;
      d0 += (double)sv[e] * (double)Wkeep[d * 2];
      d1 += (double)sv[e] * (double)Wkeep[d * 2 + 1];
    }
    d0 = wredd(d0);
    d1 = wredd(d1);
    int keepi = 0;
    if (lane == 0) keepi = ((d1 + (double)gk[(b * NSn + i) * 2 + 1]) > (d0 + (double)gk[(b * NSn + i) * 2])) ? 1 : 0;
    keepi = __shfl(keepi, 0);
    if (!keepi) {
#pragma unroll
      for (int e = 0; e < 8; ++e) { srow[lane * 8 + e] = 0.0f; sv[e] = 0.0f; }
    }
    double pw = 0.0, pb = 0.0;
#pragma unroll
    for (int e = 0; e < 8; ++e) {
      int d = lane * 8 + e;
      pw += (double)sv[e] * (double)lnw[d];
      pb += (double)sv[e] * (double)lnb[d];
    }
    pw = wredd(pw);
    pb = wredd(pb);
    if (lane == 0) { swdL[i] = pw; sbdL[i] = pb; }
  }

  float acc[8] = {};
  double accd[8] = {};
  const size_t inbase = ((size_t)b * Nn + j0) * Dn;

  float pre[8];
#pragma unroll
  for (int e = 0; e < 8; ++e) {
    int idx = t + e * 256;
    int r = idx >> 4, c = idx & 15;
    pre[e] = in[inbase + (size_t)r * Dn + c];
  }
  __syncthreads();

  for (int k0 = 0; k0 < Dn; k0 += 16) {
#pragma unroll
    for (int e = 0; e < 8; ++e) {
      int idx = t + e * 256;
      int r = idx >> 4, c = idx & 15;
      xs[c][r] = pre[e] * lw[k0 + c];
    }
    __syncthreads();
    float nxt[8] = {};
    if (k0 + 16 < Dn) {
#pragma unroll
      for (int e = 0; e < 8; ++e) {
        int idx = t + e * 256;
        int r = idx >> 4, c = idx & 15;
        nxt[e] = in[inbase + (size_t)r * Dn + k0 + 16 + c];
      }
    }
#pragma unroll
    for (int kc = 0; kc < 16; ++kc) {
      float sv = sl[tx * 516 + k0 + kc];
      float4 x0 = *reinterpret_cast<const float4*>(&xs[kc][ty * 8]);
      float4 x1 = *reinterpret_cast<const float4*>(&xs[kc][ty * 8 + 4]);
      acc[0] += x0.x * sv; acc[1] += x0.y * sv; acc[2] += x0.z * sv; acc[3] += x0.w * sv;
      acc[4] += x1.x * sv; acc[5] += x1.y * sv; acc[6] += x1.z * sv; acc[7] += x1.w * sv;
    }
    if ((k0 & 127) == 112) {
#pragma unroll
      for (int e = 0; e < 8; ++e) { accd[e] += (double)acc[e]; acc[e] = 0.0f; }
    }
#pragma unroll
    for (int e = 0; e < 8; ++e) pre[e] = nxt[e];
    __syncthreads();
  }

  double sw_i = swdL[tx], sb_i = sbdL[tx];
#pragma unroll
  for (int r = 0; r < 8; ++r) {
    int j = ty * 8 + r;
    double rsj = (double)rsig[(size_t)b * Nn + j0 + j];
    double muj = (double)mu[(size_t)b * Nn + j0 + j];
    double g = (double)g_route[((size_t)b * NSn + tx) * Nn + j0 + j];
    lgd[j][tx] = (double)kScale * (rsj * accd[r] + sb_i - muj * rsj * sw_i) + g;
  }
  __syncthreads();
  if (t < 128) {
    double best = lgd[t][0];
    int bi = 0;
#pragma unroll
    for (int i = 1; i < 16; ++i) {
      double v = lgd[t][i];
      if (v > best) { best = v; bi = i; }
    }
    besti[t] = bi;
  }
  __syncthreads();
  for (int idx = t; idx < 128 * 128; idx += 256) {
    int j = idx >> 7, c = idx & 127;
    *reinterpret_cast<float4*>(&out[inbase + (size_t)j * Dn + c * 4]) =
        *reinterpret_cast<const float4*>(&sl[besti[j] * 516 + c * 4]);
  }
}

extern "C" void kernel_launch(void* const* d_in, const int* in_sizes, int n_in,
                              void* d_out, int out_size, void* d_ws, size_t ws_size,
                              hipStream_t stream) {
  (void)in_sizes; (void)n_in; (void)out_size; (void)ws_size;
  const float* in = (const float*)d_in[0];
  const float* slots_mu = (const float*)d_in[1];
  const float* slots_ls = (const float*)d_in[2];
  const float* ln_in_w = (const float*)d_in[3];
  const float* ln_in_b = (const float*)d_in[4];
  const float* ln_s_w = (const float*)d_in[5];
  const float* ln_s_b = (const float*)d_in[6];
  const float* ln_ff_w = (const float*)d_in[7];
  const float* ln_ff_b = (const float*)d_in[8];
  const float* Wq = (const float*)d_in[9];
  const float* bq = (const float*)d_in[10];
  const float* Wk = (const float*)d_in[11];
  const float* bk = (const float*)d_in[12];
  const float* Wv = (const float*)d_in[13];
  const float* bv = (const float*)d_in[14];
  const float* Wc = (const float*)d_in[15];
  const float* bc = (const float*)d_in[16];
  const float* Wih = (const float*)d_in[17];
  const float* bih = (const float*)d_in[18];
  const float* Whh = (const float*)d_in[19];
  const float* bhh = (const float*)d_in[20];
  const float* W1 = (const float*)d_in[21];
  const float* b1 = (const float*)d_in[22];
  const float* W2 = (const float*)d_in[23];
  const float* b2 = (const float*)d_in[24];
  const float* Wkeep = (const float*)d_in[25];
  const float* noise = (const float*)d_in[26];
  const float* g_keep = (const float*)d_in[27];
  const float* g_route = (const float*)d_in[28];
  float* out = (float*)d_out;
  unsigned short* inTu = (unsigned short*)d_out;   // scratch during iterations; overwritten by k_route_out

  char* wptr = (char*)d_ws;
  auto alloc = [&](size_t bytes) {
    char* p = wptr;
    wptr += (bytes + 255) & ~(size_t)255;
    return p;
  };
  float* mu = (float*)alloc((size_t)Bn * Nn * 4);
  float* rsig = (float*)alloc((size_t)Bn * Nn * 4);
  float* psum = (float*)alloc((size_t)Bn * Nn * 8 * 4);
  float* psqs = (float*)alloc((size_t)Bn * Nn * 8 * 4);
  float* slots = (float*)alloc((size_t)Bn * NSn * Dn * 4);
  float* sln = (float*)alloc((size_t)Bn * NSn * Dn * 4);
  unsigned short* qkt = (unsigned short*)alloc((size_t)Bn * HIn * Dn * 2);
  float* alpha = (float*)alloc((size_t)Bn * HIn * 4);
  float* beta = (float*)alloc((size_t)Bn * HIn * 4);
  unsigned short* Abuf = (unsigned short*)alloc((size_t)Bn * HIn * Nn * 2);
  unsigned short* Xp = (unsigned short*)alloc((size_t)Bn * Nn * Dn * 2);
  float* Spart = (float*)alloc((size_t)Bn * 32 * HIn * 4);
  float* c1part = (float*)alloc((size_t)Bn * 32 * HIn * 4);
  float* AXp = (float*)alloc((size_t)2 * Bn * HIn * Dn * 4);
  float* updb = (float*)alloc((size_t)Bn * NSn * Dn * 4);
  float* gibuf = (float*)alloc((size_t)Bn * NSn * 1536 * 4);
  float* ghbuf = (float*)alloc((size_t)Bn * NSn * 1536 * 4);
  float* hbuf = (float*)alloc((size_t)Bn * NSn * 2048 * 4);
  float* ffp = (float*)alloc((size_t)4 * 512 * 512 * 4);
  float* T1 = (float*)alloc((size_t)Dn * 1536 * 4);
  float* WhhT = (float*)alloc((size_t)Dn * 1536 * 4);
  float* bcih = (float*)alloc((size_t)1536 * 4);
  float* Ms = (float*)alloc((size_t)Dn * 4096 * 4);
  float* vb_raw = (float*)alloc((size_t)4096 * 4);
  float* vb_s = (float*)alloc((size_t)4096 * 4);
  float* avec = (float*)alloc((size_t)4096 * 4);
  float* bvec = (float*)alloc((size_t)4096 * 4);
  float* aconst = (float*)alloc((size_t)8 * 4);
  float* bconst = (float*)alloc((size_t)8 * 4);

  // prologue
  k_tsplit<<<dim3(Nn / 64, Dn / 64, Bn), 256, 0, stream>>>(in, inTu, Xp, psum, psqs);
  k_gemm_sm<true, false, false><<<dim3(24, 8), 256, 0, stream>>>(Wc, Wih, nullptr, T1, 1536, 512);
  k_transp<<<dim3(512 / 64, 1536 / 64), 256, 0, stream>>>(Whh, WhhT, 1536, 512);
  k_vbias_bcih<<<8, 256, 0, stream>>>(Wk, bq, ln_in_w, vb_raw, vb_s, bc, Wih, bih, bcih);
  k_mh<<<dim3(8, 8, 8), 256, 0, stream>>>(Wq, Wk, Ms);
  k_mfold_consts<<<17, 256, 0, stream>>>(Ms, Wq, bk, ln_in_w, ln_in_b, avec, bvec,
                                         vb_raw, bq, aconst, bconst);
  k_initln<<<Bn * NSn + Bn * Nn / 256, 256, 0, stream>>>(slots_mu, slots_ls, noise, ln_s_w, ln_s_b,
                                                         slots, sln, psum, psqs, mu, rsig);

  for (int it = 0; it < 3; ++it) {
    k_qum_ab<<<dim3(96, 8), 256, 0, stream>>>(sln, Ms, vb_s, qkt, avec, bvec, aconst, bconst, alpha, beta);
    k_dots<<<dim3(Nn / 128, Bn), 256, 0, stream>>>(Xp, qkt, alpha, beta, mu, rsig, Abuf, Spart, c1part);
    k_ax<<<dim3(Dn / 64, 2, Bn), 256, 0, stream>>>(Abuf, inTu, AXp);
    k_updS<<<dim3(HIn, Bn), 256, 0, stream>>>(AXp, Spart, c1part, ln_in_w, ln_in_b, Wv, bv, updb);
    k_ggm<<<dim3(24, 8, 2), 256, 0, stream>>>(updb, T1, bcih, slots, WhhT, bhh, gibuf, ghbuf);
    k_gruln<<<Bn * NSn, 256, 0, stream>>>(gibuf, ghbuf, slots, sln, ln_ff_w, ln_ff_b);
    k_mm<true, false><<<dim3(32, 8, 1), 256, 0, stream>>>(sln, 512, W1, 2048, b1, hbuf, 2048, 512);
    k_mm<false, true><<<dim3(8, 8, 4), 256, 0, stream>>>(hbuf, 2048, W2, 512, nullptr, ffp, 512, 512);
    k_w2ln<<<Bn * NSn, 256, 0, stream>>>(ffp, b2, slots, sln, ln_s_w, ln_s_b);
  }

  k_route_out<<<dim3(Nn / 128, Bn), 256, 0, stream>>>(in, slots, ln_in_w, ln_in_b, Wkeep, g_keep,
                                                      mu, rsig, g_route, out);
}

// Round 22
// 1069.704 us; speedup vs baseline: 1.4629x; 1.4629x over previous
//
#include <hip/hip_runtime.h>
#include <hip/hip_bf16.h>
#include <math.h>

constexpr int Bn = 32, Nn = 4096, Dn = 512, NSn = 16, HIn = 128;
constexpr float kScale = 0.04419417382415922f; // 512^-0.5
constexpr float kEps = 1e-8f;

typedef __attribute__((ext_vector_type(8))) short short8;
typedef __attribute__((ext_vector_type(4))) float f32x4;

__device__ __forceinline__ float wred(float v) {
#pragma unroll
  for (int m = 32; m > 0; m >>= 1) v += __shfl_xor(v, m);
  return v;
}
__device__ __forceinline__ double wredd(double v) {
#pragma unroll
  for (int m = 32; m > 0; m >>= 1) v += __shfl_xor(v, m);
  return v;
}

// ---- bf16 helpers (RNE) ----
__device__ __forceinline__ unsigned short f2bf(float x) {
  unsigned u = __float_as_uint(x);
  unsigned r = (u + 0x7fffu + ((u >> 16) & 1u)) >> 16;
  return (unsigned short)r;
}
__device__ __forceinline__ float bf2f(unsigned short h) {
  return __uint_as_float(((unsigned)h) << 16);
}
__device__ __forceinline__ unsigned packhm(float x) {
  unsigned short h = f2bf(x);
  unsigned short m = f2bf(x - bf2f(h));
  return (unsigned)h | ((unsigned)m << 16);
}
__device__ __forceinline__ unsigned pack2x(float x0, float x1, unsigned& mo) {
  unsigned p0 = packhm(x0), p1 = packhm(x1);
  mo = (p0 >> 16) | (p1 & 0xffff0000u);
  return (p0 & 0xffffu) | (p1 << 16);
}

// ---------------- transpose + bf16-hi + rowstat partials (inT u16) ----------------
__global__ __launch_bounds__(256) void k_tsplit(const float* __restrict__ in, unsigned short* __restrict__ inT,
                                                float* __restrict__ psum, float* __restrict__ psqs) {
  __shared__ float tile[64][65];
  int b = blockIdx.z, j0 = blockIdx.x * 64, d0 = blockIdx.y * 64;
  int t = threadIdx.x;
  int rr = t >> 4, c4 = (t & 15) * 4;
  float4 v4[4];
#pragma unroll
  for (int e = 0; e < 4; ++e) {
    int r = e * 16 + rr;
    v4[e] = *reinterpret_cast<const float4*>(&in[((size_t)b * Nn + j0 + r) * Dn + d0 + c4]);
    tile[r][c4] = v4[e].x; tile[r][c4 + 1] = v4[e].y;
    tile[r][c4 + 2] = v4[e].z; tile[r][c4 + 3] = v4[e].w;
  }
  __syncthreads();
  float rs_s, rs_q;
  {
    int r = t >> 2, q = t & 3;
    float s = 0.0f, qq = 0.0f;
#pragma unroll
    for (int c = 0; c < 16; ++c) {
      float x = tile[r][q * 16 + c];
      s += x; qq += x * x;
    }
    s += __shfl_xor(s, 1); s += __shfl_xor(s, 2);
    qq += __shfl_xor(qq, 1); qq += __shfl_xor(qq, 2);
    rs_s = s; rs_q = qq;
  }
  unsigned short pv[16];
#pragma unroll
  for (int e = 0; e < 4; ++e) {
    pv[e * 4 + 0] = f2bf(v4[e].x);
    pv[e * 4 + 1] = f2bf(v4[e].y);
    pv[e * 4 + 2] = f2bf(v4[e].z);
    pv[e * 4 + 3] = f2bf(v4[e].w);
  }
  __syncthreads();
  unsigned short (*u16t)[130] = reinterpret_cast<unsigned short(*)[130]>(tile);
#pragma unroll
  for (int e = 0; e < 4; ++e) {
    int r = e * 16 + rr;
    u16t[r][c4] = pv[e * 4 + 0]; u16t[r][c4 + 1] = pv[e * 4 + 1];
    u16t[r][c4 + 2] = pv[e * 4 + 2]; u16t[r][c4 + 3] = pv[e * 4 + 3];
  }
  {
    int r = t >> 2, q = t & 3;
    if (q == 0) {
      size_t pi = ((size_t)b * Nn + j0 + r) * 8 + blockIdx.y;
      psum[pi] = rs_s;
      psqs[pi] = rs_q;
    }
  }
  __syncthreads();
#pragma unroll
  for (int e = 0; e < 4; ++e) {
    int dloc = e * 16 + rr;
    unsigned short o0 = u16t[c4][dloc], o1 = u16t[c4 + 1][dloc];
    unsigned short o2 = u16t[c4 + 2][dloc], o3 = u16t[c4 + 3][dloc];
    uint2 o;
    o.x = (unsigned)o0 | ((unsigned)o1 << 16);
    o.y = (unsigned)o2 | ((unsigned)o3 << 16);
    *reinterpret_cast<uint2*>(&inT[((size_t)b * Dn + d0 + dloc) * Nn + j0 + c4]) = o;
  }
}

// ---------------- slots init + LN_s fused (+ merged rowstat reduce) ----------------
__global__ __launch_bounds__(256) void k_initln(const float* __restrict__ smu, const float* __restrict__ sls,
                                                const float* __restrict__ noise,
                                                const float* __restrict__ lnsw, const float* __restrict__ lnsb,
                                                float* __restrict__ slots, float* __restrict__ sln,
                                                const float* __restrict__ psum, const float* __restrict__ psqs,
                                                float* __restrict__ mu, float* __restrict__ rsig) {
  int t = threadIdx.x;
  if (blockIdx.x >= Bn * NSn) {
    int row = (blockIdx.x - Bn * NSn) * 256 + t;
    float s = 0.0f, q = 0.0f;
#pragma unroll
    for (int e = 0; e < 8; ++e) {
      s += psum[(size_t)row * 8 + e];
      q += psqs[(size_t)row * 8 + e];
    }
    float m = s * (1.0f / 512.0f);
    float var = q * (1.0f / 512.0f) - m * m;
    mu[row] = m;
    rsig[row] = 1.0f / sqrtf(var + 1e-5f);
    return;
  }
  int r = blockIdx.x;
  __shared__ float red[8];
  float sn[2];
#pragma unroll
  for (int j = 0; j < 2; ++j) {
    int c = j * 256 + t;
    sn[j] = smu[c] + expf(sls[c]) * noise[(size_t)r * Dn + c];
  }
  float s = sn[0] + sn[1], q = sn[0] * sn[0] + sn[1] * sn[1];
  s = wred(s); q = wred(q);
  if ((t & 63) == 0) { red[t >> 6] = s; red[4 + (t >> 6)] = q; }
  __syncthreads();
  float S = red[0] + red[1] + red[2] + red[3];
  float Q = red[4] + red[5] + red[6] + red[7];
  float m = S * (1.0f / 512.0f);
  float rs = 1.0f / sqrtf(Q * (1.0f / 512.0f) - m * m + 1e-5f);
#pragma unroll
  for (int j = 0; j < 2; ++j) {
    int c = j * 256 + t;
    slots[(size_t)r * Dn + c] = sn[j];
    sln[(size_t)r * Dn + c] = (sn[j] - m) * rs * lnsw[c] + lnsb[c];
  }
}

// ---------------- small GEMM with register prefetch (f32 path, prologue T1) ----------------
template <bool TRANS, bool RELU, bool ADD>
__global__ __launch_bounds__(256) void k_gemm_sm(const float* __restrict__ A, const float* __restrict__ W,
                                                 const float* __restrict__ bias, float* __restrict__ out,
                                                 int Nc, int K) {
  __shared__ float as_[64][17];
  __shared__ float ws_[16][65];
  int m0 = blockIdx.y * 64, n0 = blockIdx.x * 64;
  int t = threadIdx.x, tx = t & 15, ty = t >> 4;
  float acc[4][4] = {};
  float pa[4], pw[4];
  auto loadA = [&](int k0) {
#pragma unroll
    for (int e = 0; e < 4; ++e) {
      int idx = t + e * 256;
      int r = idx >> 4, c = idx & 15;
      pa[e] = A[(size_t)(m0 + r) * K + k0 + c];
    }
  };
  auto loadW = [&](int k0) {
#pragma unroll
    for (int e = 0; e < 4; ++e) {
      int idx = t + e * 256;
      if (!TRANS) {
        int r = idx >> 6, c = idx & 63;
        pw[e] = W[(size_t)(k0 + r) * Nc + n0 + c];
      } else {
        int r = idx >> 4, c = idx & 15;
        pw[e] = W[(size_t)(n0 + r) * K + k0 + c];
      }
    }
  };
  loadA(0); loadW(0);
  for (int k0 = 0; k0 < K; k0 += 16) {
#pragma unroll
    for (int e = 0; e < 4; ++e) {
      int idx = t + e * 256;
      int r = idx >> 4, c = idx & 15;
      as_[r][c] = pa[e];
    }
#pragma unroll
    for (int e = 0; e < 4; ++e) {
      int idx = t + e * 256;
      if (!TRANS) {
        int r = idx >> 6, c = idx & 63;
        ws_[r][c] = pw[e];
      } else {
        int r = idx >> 4, c = idx & 15;
        ws_[c][r] = pw[e];
      }
    }
    __syncthreads();
    if (k0 + 16 < K) { loadA(k0 + 16); loadW(k0 + 16); }
#pragma unroll
    for (int kc = 0; kc < 16; ++kc) {
      float av[4], wv[4];
#pragma unroll
      for (int i = 0; i < 4; ++i) av[i] = as_[ty * 4 + i][kc];
#pragma unroll
      for (int j = 0; j < 4; ++j) wv[j] = ws_[kc][tx * 4 + j];
#pragma unroll
      for (int i = 0; i < 4; ++i)
#pragma unroll
        for (int j = 0; j < 4; ++j) acc[i][j] += av[i] * wv[j];
    }
    __syncthreads();
  }
#pragma unroll
  for (int i = 0; i < 4; ++i)
#pragma unroll
    for (int j = 0; j < 4; ++j) {
      int m = m0 + ty * 4 + i, n = n0 + tx * 4 + j;
      float v = acc[i][j] + (bias ? bias[n] : 0.0f);
      if (RELU) v = fmaxf(v, 0.0f);
      if (ADD) v += out[(size_t)m * Nc + n];
      out[(size_t)m * Nc + n] = v;
    }
}

// ---------------- transpose src[R][C] -> dst[C][R] (prologue, WhhT) ----------------
__global__ __launch_bounds__(256) void k_transp(const float* __restrict__ src, float* __restrict__ dst,
                                                int R, int C) {
  __shared__ float tile[64][65];
  int j0 = blockIdx.x * 64, i0 = blockIdx.y * 64;
  int t = threadIdx.x;
#pragma unroll
  for (int e = 0; e < 16; ++e) {
    int idx = t + e * 256;
    int r = idx >> 6, c = idx & 63;
    tile[r][c] = src[(size_t)(i0 + r) * C + j0 + c];
  }
  __syncthreads();
#pragma unroll
  for (int e = 0; e < 16; ++e) {
    int idx = t + e * 256;
    int r = idx >> 6, c = idx & 63;
    dst[(size_t)(j0 + r) * R + i0 + c] = tile[c][r];
  }
}

// ---------------- split-bf16 MFMA small GEMM: 64m x 64n tiles, K runtime ----------------
template <bool RELU, bool PARTIAL>
__global__ __launch_bounds__(256) void k_mm(const float* __restrict__ A, int lda,
                                            const float* __restrict__ W, int ldw,
                                            const float* __restrict__ bias,
                                            float* __restrict__ out, int ldo, int K) {
  __shared__ __align__(16) unsigned short as_h[64][40];
  __shared__ __align__(16) unsigned short as_m[64][40];
  __shared__ __align__(16) unsigned short ws_h[64][40];
  __shared__ __align__(16) unsigned short ws_m[64][40];
  int n0 = blockIdx.x * 64, m0 = blockIdx.y * 64, kbase = blockIdx.z * K;
  int t = threadIdx.x, w = t >> 6, l = t & 63;
  int lc = l & 15, lg = l >> 4, koff = lg * 8;

  f32x4 acc[4];
#pragma unroll
  for (int s = 0; s < 4; ++s) acc[s] = {0.0f, 0.0f, 0.0f, 0.0f};

  float2 na[4];
  float nw0[4], nw1[4];
  auto loadA = [&](int k0) {
#pragma unroll
    for (int e = 0; e < 4; ++e) {
      int idx = t + e * 256;
      int m = idx >> 4, kp = (idx & 15) * 2;
      na[e] = *reinterpret_cast<const float2*>(&A[(size_t)(m0 + m) * lda + kbase + k0 + kp]);
    }
  };
  auto loadW = [&](int k0) {
#pragma unroll
    for (int e = 0; e < 4; ++e) {
      int idx = t + e * 256;
      int kp = idx >> 6, n = idx & 63;
      nw0[e] = W[(size_t)(kbase + k0 + 2 * kp) * ldw + n0 + n];
      nw1[e] = W[(size_t)(kbase + k0 + 2 * kp + 1) * ldw + n0 + n];
    }
  };
  loadA(0); loadW(0);

  for (int k0 = 0; k0 < K; k0 += 32) {
#pragma unroll
    for (int e = 0; e < 4; ++e) {
      int idx = t + e * 256;
      int m = idx >> 4, kp = (idx & 15) * 2;
      unsigned mm;
      unsigned hm = pack2x(na[e].x, na[e].y, mm);
      *reinterpret_cast<unsigned*>(&as_h[m][kp]) = hm;
      *reinterpret_cast<unsigned*>(&as_m[m][kp]) = mm;
    }
#pragma unroll
    for (int e = 0; e < 4; ++e) {
      int idx = t + e * 256;
      int kp = idx >> 6, n = idx & 63;
      unsigned mm;
      unsigned hm = pack2x(nw0[e], nw1[e], mm);
      *reinterpret_cast<unsigned*>(&ws_h[n][kp * 2]) = hm;
      *reinterpret_cast<unsigned*>(&ws_m[n][kp * 2]) = mm;
    }
    __syncthreads();
    if (k0 + 32 < K) { loadA(k0 + 32); loadW(k0 + 32); }
    short8 ah = *reinterpret_cast<const short8*>(&as_h[w * 16 + lc][koff]);
    short8 am = *reinterpret_cast<const short8*>(&as_m[w * 16 + lc][koff]);
#pragma unroll
    for (int s = 0; s < 4; ++s) {
      short8 bh = *reinterpret_cast<const short8*>(&ws_h[s * 16 + lc][koff]);
      short8 bm = *reinterpret_cast<const short8*>(&ws_m[s * 16 + lc][koff]);
      acc[s] = __builtin_amdgcn_mfma_f32_16x16x32_bf16(ah, bh, acc[s], 0, 0, 0);
      acc[s] = __builtin_amdgcn_mfma_f32_16x16x32_bf16(ah, bm, acc[s], 0, 0, 0);
      acc[s] = __builtin_amdgcn_mfma_f32_16x16x32_bf16(am, bh, acc[s], 0, 0, 0);
    }
    __syncthreads();
  }

#pragma unroll
  for (int s = 0; s < 4; ++s) {
#pragma unroll
    for (int r = 0; r < 4; ++r) {
      int m = m0 + w * 16 + lg * 4 + r;
      int n = n0 + s * 16 + lc;
      float v = acc[s][r] + (bias ? bias[n] : 0.0f);
      if (RELU) v = fmaxf(v, 0.0f);
      if (PARTIAL)
        out[((size_t)blockIdx.z * 512 + m) * 512 + n] = v;
      else
        out[(size_t)m * ldo + n] = v;
    }
  }
}

// ---------------- fused GRU-gate GEMMs: z=0 gi = upd@T1+bcih, z=1 gh = slots@WhhT+bhh ----------------
__global__ __launch_bounds__(256) void k_ggm(const float* __restrict__ updb, const float* __restrict__ T1,
                                             const float* __restrict__ bcih, const float* __restrict__ slots,
                                             const float* __restrict__ WhhT, const float* __restrict__ bhh,
                                             float* __restrict__ gi, float* __restrict__ gh) {
  bool z = (blockIdx.z == 1);
  const float* A = z ? slots : updb;
  const float* W = z ? WhhT : T1;
  const float* bias = z ? bhh : bcih;
  float* out = z ? gh : gi;
  __shared__ __align__(16) unsigned short as_h[64][40];
  __shared__ __align__(16) unsigned short as_m[64][40];
  __shared__ __align__(16) unsigned short ws_h[64][40];
  __shared__ __align__(16) unsigned short ws_m[64][40];
  int n0 = blockIdx.x * 64, m0 = blockIdx.y * 64;
  int t = threadIdx.x, w = t >> 6, l = t & 63;
  int lc = l & 15, lg = l >> 4, koff = lg * 8;

  f32x4 acc[4];
#pragma unroll
  for (int s = 0; s < 4; ++s) acc[s] = {0.0f, 0.0f, 0.0f, 0.0f};

  float2 na[4];
  float nw0[4], nw1[4];
  auto loadA = [&](int k0) {
#pragma unroll
    for (int e = 0; e < 4; ++e) {
      int idx = t + e * 256;
      int m = idx >> 4, kp = (idx & 15) * 2;
      na[e] = *reinterpret_cast<const float2*>(&A[(size_t)(m0 + m) * 512 + k0 + kp]);
    }
  };
  auto loadW = [&](int k0) {
#pragma unroll
    for (int e = 0; e < 4; ++e) {
      int idx = t + e * 256;
      int kp = idx >> 6, n = idx & 63;
      nw0[e] = W[(size_t)(k0 + 2 * kp) * 1536 + n0 + n];
      nw1[e] = W[(size_t)(k0 + 2 * kp + 1) * 1536 + n0 + n];
    }
  };
  loadA(0); loadW(0);

  for (int k0 = 0; k0 < 512; k0 += 32) {
#pragma unroll
    for (int e = 0; e < 4; ++e) {
      int idx = t + e * 256;
      int m = idx >> 4, kp = (idx & 15) * 2;
      unsigned mm;
      unsigned hm = pack2x(na[e].x, na[e].y, mm);
      *reinterpret_cast<unsigned*>(&as_h[m][kp]) = hm;
      *reinterpret_cast<unsigned*>(&as_m[m][kp]) = mm;
    }
#pragma unroll
    for (int e = 0; e < 4; ++e) {
      int idx = t + e * 256;
      int kp = idx >> 6, n = idx & 63;
      unsigned mm;
      unsigned hm = pack2x(nw0[e], nw1[e], mm);
      *reinterpret_cast<unsigned*>(&ws_h[n][kp * 2]) = hm;
      *reinterpret_cast<unsigned*>(&ws_m[n][kp * 2]) = mm;
    }
    __syncthreads();
    if (k0 + 32 < 512) { loadA(k0 + 32); loadW(k0 + 32); }
    short8 ah = *reinterpret_cast<const short8*>(&as_h[w * 16 + lc][koff]);
    short8 am = *reinterpret_cast<const short8*>(&as_m[w * 16 + lc][koff]);
#pragma unroll
    for (int s = 0; s < 4; ++s) {
      short8 bh = *reinterpret_cast<const short8*>(&ws_h[s * 16 + lc][koff]);
      short8 bm = *reinterpret_cast<const short8*>(&ws_m[s * 16 + lc][koff]);
      acc[s] = __builtin_amdgcn_mfma_f32_16x16x32_bf16(ah, bh, acc[s], 0, 0, 0);
      acc[s] = __builtin_amdgcn_mfma_f32_16x16x32_bf16(ah, bm, acc[s], 0, 0, 0);
      acc[s] = __builtin_amdgcn_mfma_f32_16x16x32_bf16(am, bh, acc[s], 0, 0, 0);
    }
    __syncthreads();
  }

#pragma unroll
  for (int s = 0; s < 4; ++s) {
#pragma unroll
    for (int r = 0; r < 4; ++r) {
      int m = m0 + w * 16 + lg * 4 + r;
      int n = n0 + s * 16 + lc;
      out[(size_t)m * 1536 + n] = acc[s][r] + bias[n];
    }
  }
}

// ---------------- qkt = sln @ Ms + vb_s via MFMA, u16 hi-only out (+ merged alpha/beta) ----------------
__global__ __launch_bounds__(256) void k_qum_ab(const float* __restrict__ A, const float* __restrict__ Ms,
                                                const float* __restrict__ vb_s, unsigned short* __restrict__ qkt,
                                                const float* __restrict__ avec, const float* __restrict__ bvec,
                                                const float* __restrict__ aconst, const float* __restrict__ bconst,
                                                float* __restrict__ alpha, float* __restrict__ beta) {
  __shared__ __align__(16) unsigned short as_h[64][40];
  __shared__ __align__(16) unsigned short as_m[64][40];
  __shared__ __align__(16) unsigned short ws_h[64][40];
  __shared__ __align__(16) unsigned short ws_m[64][40];
  int t = threadIdx.x, w = t >> 6, l = t & 63;

  if (blockIdx.x >= 64) {
    int abid = (blockIdx.x - 64) * 8 + blockIdx.y;
    int lane = l;
#pragma unroll
    for (int gi = 0; gi < 4; ++gi) {
      int g = abid * 16 + w * 4 + gi;
      int hi = g & 127, b = g >> 7;
      int h = hi >> 4, i = hi & 15;
      const float4* sp = reinterpret_cast<const float4*>(A + (size_t)(b * NSn + i) * Dn) + lane * 2;
      const float4* ap = reinterpret_cast<const float4*>(avec + h * 512) + lane * 2;
      const float4* bp = reinterpret_cast<const float4*>(bvec + h * 512) + lane * 2;
      float4 s0 = sp[0], s1 = sp[1], a0 = ap[0], a1 = ap[1], b0 = bp[0], b1 = bp[1];
      float pa = s0.x*a0.x + s0.y*a0.y + s0.z*a0.z + s0.w*a0.w + s1.x*a1.x + s1.y*a1.y + s1.z*a1.z + s1.w*a1.w;
      float pb = s0.x*b0.x + s0.y*b0.y + s0.z*b0.z + s0.w*b0.w + s1.x*b1.x + s1.y*b1.y + s1.z*b1.z + s1.w*b1.w;
      pa = wred(pa); pb = wred(pb);
      if (lane == 0) {
        alpha[g] = pa + aconst[h];
        beta[g] = pb + bconst[h];
      }
    }
    return;
  }

  int n0 = blockIdx.x * 64, m0 = blockIdx.y * 64;
  int lc = l & 15, lg = l >> 4, koff = lg * 8;

  f32x4 acc[4];
#pragma unroll
  for (int s = 0; s < 4; ++s) acc[s] = {0.0f, 0.0f, 0.0f, 0.0f};

  float2 na[4];
  float nw0[4], nw1[4];
  auto loadA = [&](int k0) {
#pragma unroll
    for (int e = 0; e < 4; ++e) {
      int idx = t + e * 256;
      int m = idx >> 4, kp = (idx & 15) * 2;
      na[e] = *reinterpret_cast<const float2*>(&A[(size_t)(m0 + m) * 512 + k0 + kp]);
    }
  };
  auto loadW = [&](int k0) {
#pragma unroll
    for (int e = 0; e < 4; ++e) {
      int idx = t + e * 256;
      int kp = idx >> 6, n = idx & 63;
      nw0[e] = Ms[(size_t)(k0 + 2 * kp) * 4096 + n0 + n];
      nw1[e] = Ms[(size_t)(k0 + 2 * kp + 1) * 4096 + n0 + n];
    }
  };
  loadA(0); loadW(0);

  for (int k0 = 0; k0 < 512; k0 += 32) {
#pragma unroll
    for (int e = 0; e < 4; ++e) {
      int idx = t + e * 256;
      int m = idx >> 4, kp = (idx & 15) * 2;
      unsigned mm;
      unsigned hm = pack2x(na[e].x, na[e].y, mm);
      *reinterpret_cast<unsigned*>(&as_h[m][kp]) = hm;
      *reinterpret_cast<unsigned*>(&as_m[m][kp]) = mm;
    }
#pragma unroll
    for (int e = 0; e < 4; ++e) {
      int idx = t + e * 256;
      int kp = idx >> 6, n = idx & 63;
      unsigned mm;
      unsigned hm = pack2x(nw0[e], nw1[e], mm);
      *reinterpret_cast<unsigned*>(&ws_h[n][kp * 2]) = hm;
      *reinterpret_cast<unsigned*>(&ws_m[n][kp * 2]) = mm;
    }
    __syncthreads();
    if (k0 + 32 < 512) { loadA(k0 + 32); loadW(k0 + 32); }
    short8 ah = *reinterpret_cast<const short8*>(&as_h[w * 16 + lc][koff]);
    short8 am = *reinterpret_cast<const short8*>(&as_m[w * 16 + lc][koff]);
#pragma unroll
    for (int s = 0; s < 4; ++s) {
      short8 bh = *reinterpret_cast<const short8*>(&ws_h[s * 16 + lc][koff]);
      short8 bm = *reinterpret_cast<const short8*>(&ws_m[s * 16 + lc][koff]);
      acc[s] = __builtin_amdgcn_mfma_f32_16x16x32_bf16(ah, bh, acc[s], 0, 0, 0);
      acc[s] = __builtin_amdgcn_mfma_f32_16x16x32_bf16(ah, bm, acc[s], 0, 0, 0);
      acc[s] = __builtin_amdgcn_mfma_f32_16x16x32_bf16(am, bh, acc[s], 0, 0, 0);
    }
    __syncthreads();
  }

#pragma unroll
  for (int s = 0; s < 4; ++s) {
#pragma unroll
    for (int r = 0; r < 4; ++r) {
      int m = m0 + w * 16 + lg * 4 + r;
      int n = n0 + s * 16 + lc;
      int bb = m >> 4, isl = m & 15, h = n >> 9, d = n & 511;
      qkt[((size_t)bb * HIn + h * 16 + isl) * Dn + d] = f2bf(acc[s][r] + vb_s[n]);
    }
  }
}

// ---------------- W2 reduce + bias + residual + LN_s fused -> slots, sln ----------------
__global__ __launch_bounds__(256) void k_w2ln(const float* __restrict__ part, const float* __restrict__ b2,
                                              float* __restrict__ slots, float* __restrict__ sln,
                                              const float* __restrict__ lnsw, const float* __restrict__ lnsb) {
  int r = blockIdx.x, t = threadIdx.x;
  __shared__ float red[8];
  float sn[2];
#pragma unroll
  for (int j = 0; j < 2; ++j) {
    int c = j * 256 + t;
    size_t idx = (size_t)r * 512 + c;
    sn[j] = part[idx] + part[262144 + idx] + part[2 * 262144 + idx] + part[3 * 262144 + idx]
          + b2[c] + slots[idx];
  }
  float s = sn[0] + sn[1], q = sn[0] * sn[0] + sn[1] * sn[1];
  s = wred(s); q = wred(q);
  if ((t & 63) == 0) { red[t >> 6] = s; red[4 + (t >> 6)] = q; }
  __syncthreads();
  float S = red[0] + red[1] + red[2] + red[3];
  float Q = red[4] + red[5] + red[6] + red[7];
  float m = S * (1.0f / 512.0f);
  float rs = 1.0f / sqrtf(Q * (1.0f / 512.0f) - m * m + 1e-5f);
#pragma unroll
  for (int j = 0; j < 2; ++j) {
    int c = j * 256 + t;
    size_t idx = (size_t)r * 512 + c;
    slots[idx] = sn[j];
    sln[idx] = (sn[j] - m) * rs * lnsw[c] + lnsb[c];
  }
}

// ---------------- M_h = Wq_h @ Wk_h^T per head (raw) -> Ms[k*4096 + h*512 + d] ----------------
__global__ __launch_bounds__(256) void k_mh(const float* __restrict__ Wq, const float* __restrict__ Wk,
                                            float* __restrict__ Ms) {
  int h = blockIdx.z, k0 = blockIdx.y * 64, d0 = blockIdx.x * 64;
  __shared__ float qa[64][65];
  __shared__ float ka[64][65];
  int t = threadIdx.x, tx = t & 15, ty = t >> 4;
#pragma unroll
  for (int e = 0; e < 16; ++e) {
    int idx = t + e * 256;
    int r = idx >> 6, c = idx & 63;
    qa[c][r] = Wq[(size_t)(k0 + r) * Dn + h * 64 + c];
    ka[c][r] = Wk[(size_t)(d0 + r) * Dn + h * 64 + c];
  }
  __syncthreads();
  float acc[4][4] = {};
#pragma unroll 4
  for (int c = 0; c < 64; ++c) {
    float av[4], bv[4];
#pragma unroll
    for (int i = 0; i < 4; ++i) av[i] = qa[c][ty * 4 + i];
#pragma unroll
    for (int j = 0; j < 4; ++j) bv[j] = ka[c][tx * 4 + j];
#pragma unroll
    for (int i = 0; i < 4; ++i)
#pragma unroll
      for (int j = 0; j < 4; ++j) acc[i][j] += av[i] * bv[j];
  }
#pragma unroll
  for (int i = 0; i < 4; ++i)
#pragma unroll
    for (int j = 0; j < 4; ++j)
      Ms[(size_t)(k0 + ty * 4 + i) * 4096 + h * 512 + d0 + tx * 4 + j] = acc[i][j];
}

// ---------------- vbias + bcih merged ----------------
__global__ __launch_bounds__(256) void k_vbias_bcih(const float* __restrict__ Wk, const float* __restrict__ bq,
                                                    const float* __restrict__ lnw, float* __restrict__ vb_raw,
                                                    float* __restrict__ vb_s, const float* __restrict__ bc,
                                                    const float* __restrict__ Wih, const float* __restrict__ bih,
                                                    float* __restrict__ bcih) {
  __shared__ float cbuf[512];
  int t = threadIdx.x;
  if (blockIdx.x < 2) {
    cbuf[t] = bq[t]; cbuf[256 + t] = bq[256 + t];
    __syncthreads();
    int d = blockIdx.x * 256 + t;
    float vb[8] = {};
    const float4* wr = reinterpret_cast<const float4*>(Wk + (size_t)d * Dn);
#pragma unroll 8
    for (int c4 = 0; c4 < 128; ++c4) {
      float4 wv = wr[c4];
      int h = c4 >> 4;
      int c = c4 * 4;
      vb[h] += wv.x * cbuf[c] + wv.y * cbuf[c + 1] + wv.z * cbuf[c + 2] + wv.w * cbuf[c + 3];
    }
    float lw = lnw[d];
#pragma unroll
    for (int h = 0; h < 8; ++h) {
      vb_raw[h * 512 + d] = vb[h];
      vb_s[h * 512 + d] = kScale * lw * vb[h];
    }
  } else {
    cbuf[t] = bc[t]; cbuf[256 + t] = bc[256 + t];
    __syncthreads();
    int n = (blockIdx.x - 2) * 256 + t;
    const float4* wr = reinterpret_cast<const float4*>(Wih + (size_t)n * Dn);
    float a = 0.0f;
#pragma unroll 8
    for (int c4 = 0; c4 < 128; ++c4) {
      float4 wv = wr[c4];
      int c = c4 * 4;
      a += wv.x * cbuf[c] + wv.y * cbuf[c + 1] + wv.z * cbuf[c + 2] + wv.w * cbuf[c + 3];
    }
    bcih[n] = a + bih[n];
  }
}

// ---------------- mfold + consts merged ----------------
__global__ __launch_bounds__(256) void k_mfold_consts(float* __restrict__ Ms, const float* __restrict__ Wq,
                                                      const float* __restrict__ bk, const float* __restrict__ lnw,
                                                      const float* __restrict__ lnb, float* __restrict__ avec,
                                                      float* __restrict__ bvec, const float* __restrict__ vb_raw,
                                                      const float* __restrict__ bq, float* __restrict__ aconst,
                                                      float* __restrict__ bconst) {
  int t = threadIdx.x;
  if (blockIdx.x < 16) {
    __shared__ float lws[512], lbs[512], bks[512];
    lws[t] = lnw[t]; lws[256 + t] = lnw[256 + t];
    lbs[t] = lnb[t]; lbs[256 + t] = lnb[256 + t];
    bks[t] = bk[t]; bks[256 + t] = bk[256 + t];
    __syncthreads();
    int g = blockIdx.x * 256 + t;
    int k = g >> 3, h = g & 7;
    float* mr = Ms + (size_t)k * 4096 + h * 512;
    float mlnb = 0.0f, mlnw = 0.0f;
    for (int d = 0; d < 512; d += 4) {
      float4 m4 = *reinterpret_cast<const float4*>(mr + d);
      mlnb += m4.x * lbs[d] + m4.y * lbs[d + 1] + m4.z * lbs[d + 2] + m4.w * lbs[d + 3];
      mlnw += m4.x * lws[d] + m4.y * lws[d + 1] + m4.z * lws[d + 2] + m4.w * lws[d + 3];
      float4 o4 = {m4.x * kScale * lws[d], m4.y * kScale * lws[d + 1],
                   m4.z * kScale * lws[d + 2], m4.w * kScale * lws[d + 3]};
      *reinterpret_cast<float4*>(mr + d) = o4;
    }
    float wqdot = 0.0f;
    const float* qr = Wq + (size_t)k * Dn + h * 64;
    for (int c = 0; c < 64; c += 4) {
      float4 q4 = *reinterpret_cast<const float4*>(qr + c);
      wqdot += q4.x * bks[h * 64 + c] + q4.y * bks[h * 64 + c + 1] +
               q4.z * bks[h * 64 + c + 2] + q4.w * bks[h * 64 + c + 3];
    }
    avec[h * 512 + k] = kScale * (mlnb + wqdot);
    bvec[h * 512 + k] = kScale * mlnw;
  } else {
    __shared__ float r1[256], r2[256], r3[256];
    for (int h = 0; h < 8; ++h) {
      float p1 = 0.0f, p2 = 0.0f, p3 = 0.0f;
      for (int d = t; d < 512; d += 256) {
        float vr = vb_raw[h * 512 + d];
        p1 += lnb[d] * vr;
        p2 += lnw[d] * vr;
      }
      if (t < 64) p3 = bq[h * 64 + t] * bk[h * 64 + t];
      r1[t] = p1; r2[t] = p2; r3[t] = p3;
      __syncthreads();
      for (int s = 128; s > 0; s >>= 1) {
        if (t < s) { r1[t] += r1[t + s]; r2[t] += r2[t + s]; r3[t] += r3[t + s]; }
        __syncthreads();
      }
      if (t == 0) {
        aconst[h] = kScale * (r1[0] + r3[0]);
        bconst[h] = kScale * r2[0];
      }
      __syncthreads();
    }
  }
}

// ---------------- dots: X u16 hi from inT (transposed staging, XOR swizzle), U u16 hi ----------------
// A output: bf16-hi only (u16)
__global__ __launch_bounds__(256) void k_dots(const unsigned short* __restrict__ inT, const unsigned short* __restrict__ qkt,
                                              const float* __restrict__ alpha, const float* __restrict__ beta,
                                              const float* __restrict__ mu, const float* __restrict__ rsig,
                                              unsigned short* __restrict__ A, float* __restrict__ Spart,
                                              float* __restrict__ c1part) {
  __shared__ __align__(16) unsigned short xs_h[128][40];
  __shared__ __align__(16) unsigned short us_h[128][40];
  __shared__ __align__(16) float redbuf[1536];

  int b = blockIdx.y, jt = blockIdx.x, j0 = jt * 128;
  int t = threadIdx.x, w = t >> 6, l = t & 63;
  int lc = l & 15, lg = l >> 4, koff = lg * 8;
  const size_t tbase = (size_t)b * Dn * Nn + j0;   // + d*Nn + j
  const size_t ubase = (size_t)b * HIn * Dn;

  f32x4 acc[2][8];
#pragma unroll
  for (int i = 0; i < 2; ++i)
#pragma unroll
    for (int j2 = 0; j2 < 8; ++j2) acc[i][j2] = {0.0f, 0.0f, 0.0f, 0.0f};

  int xdl = t >> 3;          // d within chunk (0..31)
  int xj4 = (t & 7) * 4;     // j sub-base within each 32-j segment

  uint2 px[4];
  uint2 nu[4];
#pragma unroll
  for (int e = 0; e < 4; ++e)
    px[e] = *reinterpret_cast<const uint2*>(&inT[tbase + (size_t)xdl * Nn + e * 32 + xj4]);
#pragma unroll
  for (int e = 0; e < 4; ++e) {
    int idx = t + e * 256;
    int j = idx >> 3, dg = idx & 7;
    nu[e] = *reinterpret_cast<const uint2*>(&qkt[ubase + (size_t)j * Dn + dg * 4]);
  }

  for (int k0 = 0; k0 < 512; k0 += 32) {
    // X stores: transpose with XOR swizzle on d-column
#pragma unroll
    for (int e = 0; e < 4; ++e) {
      const unsigned short* pe = reinterpret_cast<const unsigned short*>(&px[e]);
#pragma unroll
      for (int i = 0; i < 4; ++i) {
        int j = e * 32 + xj4 + i;
        int ds = xdl ^ (((j >> 4) & 3) << 3);
        xs_h[j][ds] = pe[i];
      }
    }
#pragma unroll
    for (int e = 0; e < 4; ++e) {
      int idx = t + e * 256;
      int j = idx >> 3, dg = idx & 7;
      *reinterpret_cast<uint2*>(&us_h[j][dg * 4]) = nu[e];
    }
    if (k0 + 32 < 512) {
#pragma unroll
      for (int e = 0; e < 4; ++e)
        px[e] = *reinterpret_cast<const uint2*>(&inT[tbase + (size_t)(k0 + 32 + xdl) * Nn + e * 32 + xj4]);
#pragma unroll
      for (int e = 0; e < 4; ++e) {
        int idx = t + e * 256;
        int j = idx >> 3, dg = idx & 7;
        nu[e] = *reinterpret_cast<const uint2*>(&qkt[ubase + (size_t)j * Dn + k0 + 32 + dg * 4]);
      }
    }
    __syncthreads();
    int row0 = w * 32 + lc, row1 = row0 + 16;
    int sw0 = ((row0 >> 4) & 3) << 3, sw1 = ((row1 >> 4) & 3) << 3;
    short8 ah0 = *reinterpret_cast<const short8*>(&xs_h[row0][koff ^ sw0]);
    short8 ah1 = *reinterpret_cast<const short8*>(&xs_h[row1][koff ^ sw1]);
#pragma unroll
    for (int ht = 0; ht < 8; ++ht) {
      short8 bh = *reinterpret_cast<const short8*>(&us_h[ht * 16 + lc][koff]);
      acc[0][ht] = __builtin_amdgcn_mfma_f32_16x16x32_bf16(ah0, bh, acc[0][ht], 0, 0, 0);
      acc[1][ht] = __builtin_amdgcn_mfma_f32_16x16x32_bf16(ah1, bh, acc[1][ht], 0, 0, 0);
    }
    __syncthreads();
  }

  float* rsL = redbuf;
  float* muL = rsL + 128;
  float* aL = rsL + 256;
  float* bL = rsL + 384;
  float (*sredS)[128] = reinterpret_cast<float(*)[128]>(rsL + 512);
  float (*sredC)[128] = reinterpret_cast<float(*)[128]>(rsL + 512 + 4 * 128);
  if (t < 128) {
    rsL[t] = rsig[(size_t)b * Nn + j0 + t];
    muL[t] = mu[(size_t)b * Nn + j0 + t];
    aL[t] = alpha[b * HIn + t];
    bL[t] = beta[b * HIn + t];
  }
  __syncthreads();

  float sS[8] = {}, sC[8] = {};
#pragma unroll
  for (int jt2 = 0; jt2 < 2; ++jt2) {
    int jbase = w * 32 + jt2 * 16 + lg * 4;
#pragma unroll
    for (int ht = 0; ht < 8; ++ht) {
      int hi = ht * 16 + lc;
      float av = aL[hi], bv = bL[hi];
      float v[4], rs4[4], mr4[4];
#pragma unroll
      for (int r = 0; r < 4; ++r) {
        int jr = jbase + r;
        rs4[r] = rsL[jr];
        mr4[r] = muL[jr] * rs4[r];
        v[r] = acc[jt2][ht][r] * rs4[r] + av - mr4[r] * bv;
      }
      float mx[4] = {v[0], v[1], v[2], v[3]};
#pragma unroll
      for (int m = 1; m <= 8; m <<= 1)
#pragma unroll
        for (int r = 0; r < 4; ++r) mx[r] = fmaxf(mx[r], __shfl_xor(mx[r], m));
      float e4[4], ss[4];
#pragma unroll
      for (int r = 0; r < 4; ++r) { e4[r] = expf(v[r] - mx[r]); ss[r] = e4[r]; }
#pragma unroll
      for (int m = 1; m <= 8; m <<= 1)
#pragma unroll
        for (int r = 0; r < 4; ++r) ss[r] += __shfl_xor(ss[r], m);
      float ps = 0.0f, pc = 0.0f;
      float p0 = e4[0] / ss[0] + kEps, p1 = e4[1] / ss[1] + kEps;
      float p2 = e4[2] / ss[2] + kEps, p3 = e4[3] / ss[3] + kEps;
      unsigned h01 = (unsigned)f2bf(p0 * rs4[0]) | ((unsigned)f2bf(p1 * rs4[1]) << 16);
      unsigned h23 = (unsigned)f2bf(p2 * rs4[2]) | ((unsigned)f2bf(p3 * rs4[3]) << 16);
      uint2 o2 = {h01, h23};
      ps = p0 + p1 + p2 + p3;
      pc = p0 * mr4[0] + p1 * mr4[1] + p2 * mr4[2] + p3 * mr4[3];
      *reinterpret_cast<uint2*>(&A[(size_t)(b * HIn + hi) * Nn + j0 + jbase]) = o2;
      ps += __shfl_xor(ps, 16); ps += __shfl_xor(ps, 32);
      pc += __shfl_xor(pc, 16); pc += __shfl_xor(pc, 32);
      sS[ht] += ps; sC[ht] += pc;
    }
  }
  if (l < 16) {
#pragma unroll
    for (int ht = 0; ht < 8; ++ht) {
      sredS[w][ht * 16 + l] = sS[ht];
      sredC[w][ht * 16 + l] = sC[ht];
    }
  }
  __syncthreads();
  if (t < 128) {
    float s_ = sredS[0][t] + sredS[1][t] + sredS[2][t] + sredS[3][t];
    float c_ = sredC[0][t] + sredC[1][t] + sredC[2][t] + sredC[3][t];
    int sub = (b * 32 + jt) * HIn + t;
    Spart[sub] = s_;
    c1part[sub] = c_;
  }
}

// ---------------- AX = A @ X; A u16, X u16 hi; K-split x2; XCD-grouped block remap ----------------
__global__ __launch_bounds__(256) void k_ax(const unsigned short* __restrict__ Au, const unsigned short* __restrict__ inT,
                                            float* __restrict__ AXp) {
  __shared__ __align__(16) unsigned short as_h[128][40];
  __shared__ __align__(16) unsigned short xs_h[64][40];

  // remap: blocks sharing the same A half-tile (kp,b) land on the same XCD
  int lid = blockIdx.x + 8 * (blockIdx.y + 2 * blockIdx.z);   // 0..511
  int d0 = (lid >> 6) * 64;
  int rest = lid & 63;
  int kp = rest & 1, b = rest >> 1;

  int t = threadIdx.x, w = t >> 6, l = t & 63;
  int lc = l & 15, lg = l >> 4, koff = lg * 8;
  const size_t abase = (size_t)b * HIn * Nn + (size_t)kp * 2048;
  const size_t xbase = ((size_t)b * Dn + d0) * Nn + (size_t)kp * 2048;

  f32x4 acc[2][4];
#pragma unroll
  for (int i = 0; i < 2; ++i)
#pragma unroll
    for (int j2 = 0; j2 < 4; ++j2) acc[i][j2] = {0.0f, 0.0f, 0.0f, 0.0f};

  uint2 pa[4];
  uint2 px[2];
#pragma unroll
  for (int e = 0; e < 4; ++e) {
    int idx = t + e * 256;
    int hi = idx >> 3, sl = idx & 7;
    pa[e] = *reinterpret_cast<const uint2*>(&Au[abase + (size_t)hi * Nn + sl * 4]);
  }
#pragma unroll
  for (int e = 0; e < 2; ++e) {
    int idx = t + e * 256;
    int d = idx >> 3, jg = idx & 7;
    px[e] = *reinterpret_cast<const uint2*>(&inT[xbase + (size_t)d * Nn + jg * 4]);
  }

  for (int c0 = 0; c0 < 2048; c0 += 32) {
#pragma unroll
    for (int e = 0; e < 4; ++e) {
      int idx = t + e * 256;
      int hi = idx >> 3, sl = idx & 7;
      *reinterpret_cast<uint2*>(&as_h[hi][sl * 4]) = pa[e];
    }
#pragma unroll
    for (int e = 0; e < 2; ++e) {
      int idx = t + e * 256;
      int d = idx >> 3, jg = idx & 7;
      *reinterpret_cast<uint2*>(&xs_h[d][jg * 4]) = px[e];
    }
    if (c0 + 32 < 2048) {
#pragma unroll
      for (int e = 0; e < 4; ++e) {
        int idx = t + e * 256;
        int hi = idx >> 3, sl = idx & 7;
        pa[e] = *reinterpret_cast<const uint2*>(&Au[abase + (size_t)hi * Nn + c0 + 32 + sl * 4]);
      }
#pragma unroll
      for (int e = 0; e < 2; ++e) {
        int idx = t + e * 256;
        int d = idx >> 3, jg = idx & 7;
        px[e] = *reinterpret_cast<const uint2*>(&inT[xbase + (size_t)d * Nn + c0 + 32 + jg * 4]);
      }
    }
    __syncthreads();
    short8 ah0 = *reinterpret_cast<const short8*>(&as_h[w * 32 + lc][koff]);
    short8 ah1 = *reinterpret_cast<const short8*>(&as_h[w * 32 + 16 + lc][koff]);
#pragma unroll
    for (int dt = 0; dt < 4; ++dt) {
      short8 bh = *reinterpret_cast<const short8*>(&xs_h[dt * 16 + lc][koff]);
      acc[0][dt] = __builtin_amdgcn_mfma_f32_16x16x32_bf16(ah0, bh, acc[0][dt], 0, 0, 0);
      acc[1][dt] = __builtin_amdgcn_mfma_f32_16x16x32_bf16(ah1, bh, acc[1][dt], 0, 0, 0);
    }
    __syncthreads();
  }

  const size_t obase = (((size_t)kp * Bn + b) * HIn) * Dn + d0;
#pragma unroll
  for (int jt2 = 0; jt2 < 2; ++jt2) {
#pragma unroll
    for (int dt = 0; dt < 4; ++dt) {
#pragma unroll
      for (int r = 0; r < 4; ++r) {
        int hi = w * 32 + jt2 * 16 + lg * 4 + r;
        int d = dt * 16 + lc;
        AXp[obase + (size_t)hi * Dn + d] = acc[jt2][dt][r];
      }
    }
  }
}

// ---------------- upd = ((w*(G-c1)/S + b) @ Wv_h) + bv, S/c1 reduced inline ----------------
__global__ __launch_bounds__(256) void k_updS(const float* __restrict__ AXp, const float* __restrict__ Spart,
                                              const float* __restrict__ c1part, const float* __restrict__ lnw,
                                              const float* __restrict__ lnb, const float* __restrict__ Wv,
                                              const float* __restrict__ bv, float* __restrict__ upd) {
  int b = blockIdx.y, hi = blockIdx.x, h = hi >> 4, i = hi & 15;
  __shared__ float vx[512];
  __shared__ float red[256];
  __shared__ float sSC[2];
  int t = threadIdx.x;
  if (t < 64) {
    float vs = 0.0f, vc = 0.0f;
    if (t < 32) {
      vs = Spart[(size_t)(b * 32 + t) * HIn + hi];
      vc = c1part[(size_t)(b * 32 + t) * HIn + hi];
    }
    vs = wred(vs); vc = wred(vc);
    if (t == 0) { sSC[0] = vs; sSC[1] = vc; }
  }
  __syncthreads();
  float c1v = sSC[1];
  float invS = 1.0f / sSC[0];
  for (int d = t; d < Dn; d += 256) {
    float G = AXp[((size_t)(0 * Bn + b) * HIn + hi) * Dn + d]
            + AXp[((size_t)(1 * Bn + b) * HIn + hi) * Dn + d];
    vx[d] = lnw[d] * (G - c1v) * invS + lnb[d];
  }
  __syncthreads();
  int cc = t & 63, qd = t >> 6;
  float p = 0.0f;
  for (int d = qd * 128; d < qd * 128 + 128; ++d) p += vx[d] * Wv[(size_t)d * Dn + h * 64 + cc];
  red[t] = p;
  __syncthreads();
  if (qd == 0) {
    float v = red[cc] + red[64 + cc] + red[128 + cc] + red[192 + cc] + bv[h * 64 + cc];
    upd[(size_t)(b * NSn + i) * Dn + h * 64 + cc] = v;
  }
}

// ---------------- GRU pointwise + LN_ff fused ----------------
__global__ __launch_bounds__(256) void k_gruln(const float* __restrict__ gi, const float* __restrict__ gh,
                                               float* __restrict__ slots, float* __restrict__ slnff,
                                               const float* __restrict__ lnffw, const float* __restrict__ lnffb) {
  int r = blockIdx.x, t = threadIdx.x;
  __shared__ float red[8];
  float sn[2];
#pragma unroll
  for (int j = 0; j < 2; ++j) {
    int c = j * 256 + t;
    float gir = gi[(size_t)r * 1536 + c];
    float giz = gi[(size_t)r * 1536 + 512 + c];
    float gin = gi[(size_t)r * 1536 + 1024 + c];
    float ghr = gh[(size_t)r * 1536 + c];
    float ghz = gh[(size_t)r * 1536 + 512 + c];
    float ghn = gh[(size_t)r * 1536 + 1024 + c];
    float rg = 1.0f / (1.0f + expf(-(gir + ghr)));
    float zg = 1.0f / (1.0f + expf(-(giz + ghz)));
    float ng = tanhf(gin + rg * ghn);
    sn[j] = (1.0f - zg) * ng + zg * slots[(size_t)r * Dn + c];
  }
  float s = sn[0] + sn[1], q = sn[0] * sn[0] + sn[1] * sn[1];
  s = wred(s); q = wred(q);
  if ((t & 63) == 0) { red[t >> 6] = s; red[4 + (t >> 6)] = q; }
  __syncthreads();
  float S = red[0] + red[1] + red[2] + red[3];
  float Q = red[4] + red[5] + red[6] + red[7];
  float m = S * (1.0f / 512.0f);
  float rs = 1.0f / sqrtf(Q * (1.0f / 512.0f) - m * m + 1e-5f);
#pragma unroll
  for (int j = 0; j < 2; ++j) {
    int c = j * 256 + t;
    slots[(size_t)r * Dn + c] = sn[j];
    slnff[(size_t)r * Dn + c] = (sn[j] - m) * rs * lnffw[c] + lnffb[c];
  }
}

// ---------------- hard route + gather output (keep gate + scalars inlined) ----------------
__global__ __launch_bounds__(256) void k_route_out(const float* __restrict__ in, const float* __restrict__ slots,
                                                   const float* __restrict__ lnw, const float* __restrict__ lnb,
                                                   const float* __restrict__ Wkeep, const float* __restrict__ gk,
                                                   const float* __restrict__ mu, const float* __restrict__ rsig,
                                                   const float* __restrict__ g_route, float* __restrict__ out) {
  int b = blockIdx.y, j0 = blockIdx.x * 128;
  __shared__ __align__(16) float sl[16 * 516];
  __shared__ __align__(16) float lw[512];
  __shared__ __align__(16) float xs[16][132];
  __shared__ double lgd[128][17];
  __shared__ int besti[128];
  __shared__ double swdL[16], sbdL[16];
  int t = threadIdx.x, tx = t & 15, ty = t >> 4;
  int wv_ = t >> 6, lane = t & 63;

  for (int idx = t; idx < 2048; idx += 256) {
    int i = idx >> 7, c = idx & 127;
    *reinterpret_cast<float4*>(&sl[i * 516 + c * 4]) =
        *reinterpret_cast<const float4*>(&slots[(size_t)(b * NSn + i) * Dn + c * 4]);
  }
  if (t < 128)
    *reinterpret_cast<float4*>(&lw[t * 4]) = *reinterpret_cast<const float4*>(&lnw[t * 4]);
  __syncthreads();

#pragma unroll
  for (int qi = 0; qi < 4; ++qi) {
    int i = wv_ * 4 + qi;
    float* srow = &sl[i * 516];
    float sv[8];
#pragma unroll
    for (int e = 0; e < 8; ++e) sv[e] = srow[lane * 8 + e];
    double d0 = 0.0, d1 = 0.0;
#pragma unroll
    for (int e = 0; e < 8; ++e) {
      int d = lane * 8 + e;
      d0 += (double)sv[e] * (double)Wkeep[d * 2];
      d1 += (double)sv[e] * (double)Wkeep[d * 2 + 1];
    }
    d0 = wredd(d0);
    d1 = wredd(d1);
    int keepi = 0;
    if (lane == 0) keepi = ((d1 + (double)gk[(b * NSn + i) * 2 + 1]) > (d0 + (double)gk[(b * NSn + i) * 2])) ? 1 : 0;
    keepi = __shfl(keepi, 0);
    if (!keepi) {
#pragma unroll
      for (int e = 0; e < 8; ++e) { srow[lane * 8 + e] = 0.0f; sv[e] = 0.0f; }
    }
    double pw = 0.0, pb = 0.0;
#pragma unroll
    for (int e = 0; e < 8; ++e) {
      int d = lane * 8 + e;
      pw += (double)sv[e] * (double)lnw[d];
      pb += (double)sv[e] * (double)lnb[d];
    }
    pw = wredd(pw);
    pb = wredd(pb);
    if (lane == 0) { swdL[i] = pw; sbdL[i] = pb; }
  }

  float acc[8] = {};
  double accd[8] = {};
  const size_t inbase = ((size_t)b * Nn + j0) * Dn;

  float pre[8];
#pragma unroll
  for (int e = 0; e < 8; ++e) {
    int idx = t + e * 256;
    int r = idx >> 4, c = idx & 15;
    pre[e] = in[inbase + (size_t)r * Dn + c];
  }
  __syncthreads();

  for (int k0 = 0; k0 < Dn; k0 += 16) {
#pragma unroll
    for (int e = 0; e < 8; ++e) {
      int idx = t + e * 256;
      int r = idx >> 4, c = idx & 15;
      xs[c][r] = pre[e] * lw[k0 + c];
    }
    __syncthreads();
    float nxt[8] = {};
    if (k0 + 16 < Dn) {
#pragma unroll
      for (int e = 0; e < 8; ++e) {
        int idx = t + e * 256;
        int r = idx >> 4, c = idx & 15;
        nxt[e] = in[inbase + (size_t)r * Dn + k0 + 16 + c];
      }
    }
#pragma unroll
    for (int kc = 0; kc < 16; ++kc) {
      float sv = sl[tx * 516 + k0 + kc];
      float4 x0 = *reinterpret_cast<const float4*>(&xs[kc][ty * 8]);
      float4 x1 = *reinterpret_cast<const float4*>(&xs[kc][ty * 8 + 4]);
      acc[0] += x0.x * sv; acc[1] += x0.y * sv; acc[2] += x0.z * sv; acc[3] += x0.w * sv;
      acc[4] += x1.x * sv; acc[5] += x1.y * sv; acc[6] += x1.z * sv; acc[7] += x1.w * sv;
    }
    if ((k0 & 127) == 112) {
#pragma unroll
      for (int e = 0; e < 8; ++e) { accd[e] += (double)acc[e]; acc[e] = 0.0f; }
    }
#pragma unroll
    for (int e = 0; e < 8; ++e) pre[e] = nxt[e];
    __syncthreads();
  }

  double sw_i = swdL[tx], sb_i = sbdL[tx];
#pragma unroll
  for (int r = 0; r < 8; ++r) {
    int j = ty * 8 + r;
    double rsj = (double)rsig[(size_t)b * Nn + j0 + j];
    double muj = (double)mu[(size_t)b * Nn + j0 + j];
    double g = (double)g_route[((size_t)b * NSn + tx) * Nn + j0 + j];
    lgd[j][tx] = (double)kScale * (rsj * accd[r] + sb_i - muj * rsj * sw_i) + g;
  }
  __syncthreads();
  if (t < 128) {
    double best = lgd[t][0];
    int bi = 0;
#pragma unroll
    for (int i = 1; i < 16; ++i) {
      double v = lgd[t][i];
      if (v > best) { best = v; bi = i; }
    }
    besti[t] = bi;
  }
  __syncthreads();
  for (int idx = t; idx < 128 * 128; idx += 256) {
    int j = idx >> 7, c = idx & 127;
    *reinterpret_cast<float4*>(&out[inbase + (size_t)j * Dn + c * 4]) =
        *reinterpret_cast<const float4*>(&sl[besti[j] * 516 + c * 4]);
  }
}

extern "C" void kernel_launch(void* const* d_in, const int* in_sizes, int n_in,
                              void* d_out, int out_size, void* d_ws, size_t ws_size,
                              hipStream_t stream) {
  (void)in_sizes; (void)n_in; (void)out_size; (void)ws_size;
  const float* in = (const float*)d_in[0];
  const float* slots_mu = (const float*)d_in[1];
  const float* slots_ls = (const float*)d_in[2];
  const float* ln_in_w = (const float*)d_in[3];
  const float* ln_in_b = (const float*)d_in[4];
  const float* ln_s_w = (const float*)d_in[5];
  const float* ln_s_b = (const float*)d_in[6];
  const float* ln_ff_w = (const float*)d_in[7];
  const float* ln_ff_b = (const float*)d_in[8];
  const float* Wq = (const float*)d_in[9];
  const float* bq = (const float*)d_in[10];
  const float* Wk = (const float*)d_in[11];
  const float* bk = (const float*)d_in[12];
  const float* Wv = (const float*)d_in[13];
  const float* bv = (const float*)d_in[14];
  const float* Wc = (const float*)d_in[15];
  const float* bc = (const float*)d_in[16];
  const float* Wih = (const float*)d_in[17];
  const float* bih = (const float*)d_in[18];
  const float* Whh = (const float*)d_in[19];
  const float* bhh = (const float*)d_in[20];
  const float* W1 = (const float*)d_in[21];
  const float* b1 = (const float*)d_in[22];
  const float* W2 = (const float*)d_in[23];
  const float* b2 = (const float*)d_in[24];
  const float* Wkeep = (const float*)d_in[25];
  const float* noise = (const float*)d_in[26];
  const float* g_keep = (const float*)d_in[27];
  const float* g_route = (const float*)d_in[28];
  float* out = (float*)d_out;
  unsigned short* inTu = (unsigned short*)d_out;   // scratch during iterations; overwritten by k_route_out

  char* wptr = (char*)d_ws;
  auto alloc = [&](size_t bytes) {
    char* p = wptr;
    wptr += (bytes + 255) & ~(size_t)255;
    return p;
  };
  float* mu = (float*)alloc((size_t)Bn * Nn * 4);
  float* rsig = (float*)alloc((size_t)Bn * Nn * 4);
  float* psum = (float*)alloc((size_t)Bn * Nn * 8 * 4);
  float* psqs = (float*)alloc((size_t)Bn * Nn * 8 * 4);
  float* slots = (float*)alloc((size_t)Bn * NSn * Dn * 4);
  float* sln = (float*)alloc((size_t)Bn * NSn * Dn * 4);
  unsigned short* qkt = (unsigned short*)alloc((size_t)Bn * HIn * Dn * 2);
  float* alpha = (float*)alloc((size_t)Bn * HIn * 4);
  float* beta = (float*)alloc((size_t)Bn * HIn * 4);
  unsigned short* Abuf = (unsigned short*)alloc((size_t)Bn * HIn * Nn * 2);
  float* Spart = (float*)alloc((size_t)Bn * 32 * HIn * 4);
  float* c1part = (float*)alloc((size_t)Bn * 32 * HIn * 4);
  float* AXp = (float*)alloc((size_t)2 * Bn * HIn * Dn * 4);
  float* updb = (float*)alloc((size_t)Bn * NSn * Dn * 4);
  float* gibuf = (float*)alloc((size_t)Bn * NSn * 1536 * 4);
  float* ghbuf = (float*)alloc((size_t)Bn * NSn * 1536 * 4);
  float* hbuf = (float*)alloc((size_t)Bn * NSn * 2048 * 4);
  float* ffp = (float*)alloc((size_t)4 * 512 * 512 * 4);
  float* T1 = (float*)alloc((size_t)Dn * 1536 * 4);
  float* WhhT = (float*)alloc((size_t)Dn * 1536 * 4);
  float* bcih = (float*)alloc((size_t)1536 * 4);
  float* Ms = (float*)alloc((size_t)Dn * 4096 * 4);
  float* vb_raw = (float*)alloc((size_t)4096 * 4);
  float* vb_s = (float*)alloc((size_t)4096 * 4);
  float* avec = (float*)alloc((size_t)4096 * 4);
  float* bvec = (float*)alloc((size_t)4096 * 4);
  float* aconst = (float*)alloc((size_t)8 * 4);
  float* bconst = (float*)alloc((size_t)8 * 4);

  // prologue
  k_tsplit<<<dim3(Nn / 64, Dn / 64, Bn), 256, 0, stream>>>(in, inTu, psum, psqs);
  k_gemm_sm<true, false, false><<<dim3(24, 8), 256, 0, stream>>>(Wc, Wih, nullptr, T1, 1536, 512);
  k_transp<<<dim3(512 / 64, 1536 / 64), 256, 0, stream>>>(Whh, WhhT, 1536, 512);
  k_vbias_bcih<<<8, 256, 0, stream>>>(Wk, bq, ln_in_w, vb_raw, vb_s, bc, Wih, bih, bcih);
  k_mh<<<dim3(8, 8, 8), 256, 0, stream>>>(Wq, Wk, Ms);
  k_mfold_consts<<<17, 256, 0, stream>>>(Ms, Wq, bk, ln_in_w, ln_in_b, avec, bvec,
                                         vb_raw, bq, aconst, bconst);
  k_initln<<<Bn * NSn + Bn * Nn / 256, 256, 0, stream>>>(slots_mu, slots_ls, noise, ln_s_w, ln_s_b,
                                                         slots, sln, psum, psqs, mu, rsig);

  for (int it = 0; it < 3; ++it) {
    k_qum_ab<<<dim3(96, 8), 256, 0, stream>>>(sln, Ms, vb_s, qkt, avec, bvec, aconst, bconst, alpha, beta);
    k_dots<<<dim3(Nn / 128, Bn), 256, 0, stream>>>(inTu, qkt, alpha, beta, mu, rsig, Abuf, Spart, c1part);
    k_ax<<<dim3(Dn / 64, 2, Bn), 256, 0, stream>>>(Abuf, inTu, AXp);
    k_updS<<<dim3(HIn, Bn), 256, 0, stream>>>(AXp, Spart, c1part, ln_in_w, ln_in_b, Wv, bv, updb);
    k_ggm<<<dim3(24, 8, 2), 256, 0, stream>>>(updb, T1, bcih, slots, WhhT, bhh, gibuf, ghbuf);
    k_gruln<<<Bn * NSn, 256, 0, stream>>>(gibuf, ghbuf, slots, sln, ln_ff_w, ln_ff_b);
    k_mm<true, false><<<dim3(32, 8, 1), 256, 0, stream>>>(sln, 512, W1, 2048, b1, hbuf, 2048, 512);
    k_mm<false, true><<<dim3(8, 8, 4), 256, 0, stream>>>(hbuf, 2048, W2, 512, nullptr, ffp, 512, 512);
    k_w2ln<<<Bn * NSn, 256, 0, stream>>>(ffp, b2, slots, sln, ln_s_w, ln_s_b);
  }

  k_route_out<<<dim3(Nn / 128, Bn), 256, 0, stream>>>(in, slots, ln_in_w, ln_in_b, Wkeep, g_keep,
                                                      mu, rsig, g_route, out);
}